// Round 1
// baseline (5603.802 us; speedup 1.0000x reference)
//
#include <hip/hip_runtime.h>
#include <math.h>

#define MM_GELU 1
#define MM_RES 2
#define MM_SPLIT 4

// ---------------- embedding + positional encoding ----------------
__global__ __launch_bounds__(128) void embed_kernel(
    const int* __restrict__ xm, const int* __restrict__ xa,
    const int* __restrict__ xh, const int* __restrict__ xw,
    const float* __restrict__ em, const float* __restrict__ ea,
    const float* __restrict__ eh, const float* __restrict__ ew,
    float* __restrict__ x1, float* __restrict__ x2) {
  int row = blockIdx.x;      // 0..15999 = b*1000+s
  int d = threadIdx.x;       // 0..127
  int s = row % 1000;
  float v;
  if (d < 64)       v = em[xm[row]*64 + d];
  else if (d < 96)  v = ea[xa[row]*32 + (d-64)];
  else if (d < 112) v = eh[xh[row]*16 + (d-96)];
  else              v = ew[xw[row]*16 + (d-112)];
  int i = d >> 1;
  float dv = expf((float)(2*i) * (-9.21034037198f/128.f));
  float ang = (float)s * dv;
  v += (d & 1) ? cosf(ang) : sinf(ang);
  x1[row*128 + d] = v;
  x2[row*128 + d] = v;
}

// ---------------- layernorm (optional average of two inputs) ----------------
__global__ __launch_bounds__(64) void ln_kernel(
    const float* __restrict__ x, const float* __restrict__ xb,
    const float* __restrict__ g, const float* __restrict__ b,
    float* __restrict__ out) {
  int row = blockIdx.x;
  int t = threadIdx.x;       // 64 lanes, 2 elems each
  float v0 = x[row*128 + t], v1 = x[row*128 + 64 + t];
  if (xb) { v0 = 0.5f*(v0 + xb[row*128 + t]); v1 = 0.5f*(v1 + xb[row*128 + 64 + t]); }
  float sum = v0 + v1;
  #pragma unroll
  for (int o = 32; o > 0; o >>= 1) sum += __shfl_xor(sum, o);
  float mean = sum * (1.f/128.f);
  float d0 = v0 - mean, d1 = v1 - mean;
  float vs = d0*d0 + d1*d1;
  #pragma unroll
  for (int o = 32; o > 0; o >>= 1) vs += __shfl_xor(vs, o);
  float rstd = rsqrtf(vs*(1.f/128.f) + 1e-5f);
  out[row*128 + t]      = d0*rstd*g[t]    + b[t];
  out[row*128 + 64 + t] = d1*rstd*g[t+64] + b[t+64];
}

// ---------------- generic tiled f32 matmul with fused epilogue ----------------
// C[M,N] (= or +=) act(A[M,K] @ W[K,N] + bias). M % 64 == 0, K % 32 == 0.
__global__ __launch_bounds__(256) void matmul_kernel(
    const float* __restrict__ A, const float* __restrict__ W,
    const float* __restrict__ bias, float* __restrict__ C,
    int M, int N, int K, int flags) {
  __shared__ float As[64][33];                 // [row][k] transposed-ish, conflict-free
  __shared__ __align__(16) float Bs[32][64];
  int tid = threadIdx.x;
  int bm = blockIdx.x * 64;
  int bn = blockIdx.y * 64;
  int tr = (tid >> 4) * 4;
  int tc = (tid & 15) * 4;
  float acc[4][4];
  #pragma unroll
  for (int i = 0; i < 4; ++i)
    #pragma unroll
    for (int j = 0; j < 4; ++j) acc[i][j] = 0.f;
  for (int k0 = 0; k0 < K; k0 += 32) {
    #pragma unroll
    for (int i = 0; i < 8; ++i) {
      int e = tid + i*256;
      int rr = e >> 5, kk = e & 31;
      As[rr][kk] = A[(size_t)(bm + rr)*K + k0 + kk];
    }
    #pragma unroll
    for (int i = 0; i < 8; ++i) {
      int e = tid + i*256;
      int kk = e >> 6, cc = e & 63;
      int col = bn + cc;
      Bs[kk][cc] = (col < N) ? W[(size_t)(k0 + kk)*N + col] : 0.f;
    }
    __syncthreads();
    #pragma unroll
    for (int kk = 0; kk < 32; ++kk) {
      float a0 = As[tr+0][kk], a1 = As[tr+1][kk], a2 = As[tr+2][kk], a3 = As[tr+3][kk];
      float4 b4 = *(const float4*)&Bs[kk][tc];
      acc[0][0] += a0*b4.x; acc[0][1] += a0*b4.y; acc[0][2] += a0*b4.z; acc[0][3] += a0*b4.w;
      acc[1][0] += a1*b4.x; acc[1][1] += a1*b4.y; acc[1][2] += a1*b4.z; acc[1][3] += a1*b4.w;
      acc[2][0] += a2*b4.x; acc[2][1] += a2*b4.y; acc[2][2] += a2*b4.z; acc[2][3] += a2*b4.w;
      acc[3][0] += a3*b4.x; acc[3][1] += a3*b4.y; acc[3][2] += a3*b4.z; acc[3][3] += a3*b4.w;
    }
    __syncthreads();
  }
  #pragma unroll
  for (int i = 0; i < 4; ++i) {
    int row = bm + tr + i;
    #pragma unroll
    for (int j = 0; j < 4; ++j) {
      int col = bn + tc + j;
      if (col < N) {
        float val = acc[i][j];
        if (bias) val += bias[col];
        if (flags & MM_GELU) val = 0.5f*val*(1.f + erff(val*0.70710678118f));
        size_t oi;
        if (flags & MM_SPLIT) {
          int bb = row / 1000, ss = row % 1000;
          int hd = col >> 4, dd = col & 15;
          oi = (((size_t)(bb*8 + hd))*1000 + ss)*16 + dd;
        } else {
          oi = (size_t)row*N + col;
        }
        if (flags & MM_RES) C[oi] += val; else C[oi] = val;
      }
    }
  }
}

// ---------------- LSH bucket assignment ----------------
__global__ __launch_bounds__(256) void bucket_kernel(
    const float* __restrict__ qk, const float* __restrict__ rot,
    int* __restrict__ buckets) {
  int idx = blockIdx.x*256 + threadIdx.x;   // bh*1000+s
  if (idx >= 128000) return;
  int bh = idx / 1000, s = idx % 1000;
  float q[16];
  #pragma unroll
  for (int d = 0; d < 16; ++d) q[d] = qk[(bh*1000+s)*16 + d];
  #pragma unroll 1
  for (int r = 0; r < 4; ++r) {
    float rv[20];
    #pragma unroll
    for (int n = 0; n < 20; ++n) {
      float acc = 0.f;
      #pragma unroll
      for (int d = 0; d < 16; ++d) acc += q[d]*rot[(d*4 + r)*20 + n];
      rv[n] = acc;
    }
    float best = -INFINITY; int bi = 0;
    #pragma unroll
    for (int n = 0; n < 40; ++n) {
      float val = (n < 20) ? rv[n] : -rv[n-20];
      if (val > best) { best = val; bi = n; }   // strict > => first index on ties
    }
    buckets[(bh*4 + r)*1000 + s] = bi;
  }
}

// ---------------- stable counting sort per (bh, round) ----------------
__global__ __launch_bounds__(64) void sort_kernel(
    const int* __restrict__ buckets, int* __restrict__ st, int* __restrict__ undo) {
  int bh = blockIdx.x >> 2;
  int r = blockIdx.x & 3;
  const int* bkt = buckets + (bh*4 + r)*1000;
  __shared__ int cnt[40];
  __shared__ int off[40];
  int lane = threadIdx.x;
  if (lane < 40) cnt[lane] = 0;
  __syncthreads();
  for (int s = lane; s < 1000; s += 64) atomicAdd(&cnt[bkt[s]], 1);
  __syncthreads();
  if (lane == 0) {
    int acc = 0;
    for (int bb = 0; bb < 40; ++bb) { off[bb] = acc; acc += cnt[bb]; }
  }
  __syncthreads();
  int base = bh*4000 + r*1000;
  for (int c0 = 0; c0 < 1000; c0 += 64) {       // sequential chunks keep stability
    int s = c0 + lane;
    int b = (s < 1000) ? bkt[s] : -1;
    for (int bb = 0; bb < 40; ++bb) {
      unsigned long long mask = __ballot(b == bb);
      if (mask == 0ull) continue;
      int bo = off[bb];
      if (b == bb) {
        int rank = (int)__popcll(mask & ((1ull << lane) - 1ull));
        int slot = bo + rank;
        st[base + slot] = s;                    // token position of sorted slot
        undo[base + s] = r*1000 + slot;         // global slot of (r, s)
      }
      if (lane == 63) off[bb] = bo + (int)__popcll(mask);
      __syncthreads();
    }
  }
}

// ---------------- per-chunk attention (25 q x 50 kv) ----------------
__global__ __launch_bounds__(64) void attn_chunk_kernel(
    const float* __restrict__ qk, const float* __restrict__ v,
    const int* __restrict__ st, const int* __restrict__ xm,
    float* __restrict__ so, float* __restrict__ slse) {
  int blk = blockIdx.x;
  int bh = blk / 160;
  int n = blk % 160;
  int b = bh >> 3;
  int lane = threadIdx.x;
  __shared__ float SQ[25][17], BK[50][17], BV[50][17];
  __shared__ float DOT[25][50];
  __shared__ int TQ[25], TKV[50], MQ[25], MKV[50];
  int pn = (n + 159) % 160;                     // roll: chunk 0's prev is 159
  if (lane < 50) {
    int slot = (lane < 25) ? (n*25 + lane) : (pn*25 + (lane - 25));
    int t = st[bh*4000 + slot];
    TKV[lane] = t;
    int m = (xm[b*1000 + t] != 0) ? 1 : 0;
    MKV[lane] = m;
    const float* qr = qk + ((size_t)bh*1000 + t)*16;
    const float* vr = v  + ((size_t)bh*1000 + t)*16;
    float ss = 1e-9f;
    float tmp[16];
    #pragma unroll
    for (int d = 0; d < 16; ++d) { tmp[d] = qr[d]; ss += tmp[d]*tmp[d]; }
    float rsq = rsqrtf(ss);
    #pragma unroll
    for (int d = 0; d < 16; ++d) { BK[lane][d] = tmp[d]*rsq; BV[lane][d] = vr[d]; }
    if (lane < 25) {
      TQ[lane] = t; MQ[lane] = m;
      #pragma unroll
      for (int d = 0; d < 16; ++d) SQ[lane][d] = tmp[d];   // queries are raw qk
    }
  }
  __syncthreads();
  for (int p = lane; p < 1250; p += 64) {
    int qi = p / 50, ki = p % 50;
    float acc = 0.f;
    #pragma unroll
    for (int d = 0; d < 16; ++d) acc += SQ[qi][d]*BK[ki][d];
    acc *= 0.25f;                                // D^-0.5, D=16
    if (!(MQ[qi] && MKV[ki])) acc = -1e9f;       // padding
    int tq = TQ[qi], tk = TKV[ki];
    if (tq < tk) acc = -1e9f;                    // causal
    if (tq == tk) acc = -5e4f;                   // self (overrides)
    DOT[qi][ki] = acc;
  }
  __syncthreads();
  if (lane < 25) {
    float m = -INFINITY;
    for (int k = 0; k < 50; ++k) m = fmaxf(m, DOT[lane][k]);
    float sum = 0.f;
    for (int k = 0; k < 50; ++k) sum += expf(DOT[lane][k] - m);
    float lse = m + logf(sum);
    float o[16];
    #pragma unroll
    for (int d = 0; d < 16; ++d) o[d] = 0.f;
    for (int k = 0; k < 50; ++k) {
      float wt = expf(DOT[lane][k] - lse);
      #pragma unroll
      for (int d = 0; d < 16; ++d) o[d] += wt * BV[k][d];
    }
    int slot = n*25 + lane;
    float* op = so + ((size_t)bh*4000 + slot)*16;
    #pragma unroll
    for (int d = 0; d < 16; ++d) op[d] = o[d];
    slse[bh*4000 + slot] = lse;
  }
}

// ---------------- unsort + combine hash rounds + merge heads ----------------
__global__ __launch_bounds__(256) void combine_kernel(
    const float* __restrict__ so, const float* __restrict__ slse,
    const int* __restrict__ undo, float* __restrict__ ao) {
  int idx = blockIdx.x*256 + threadIdx.x;   // over BH*S*16
  if (idx >= 2048000) return;
  int d = idx & 15;
  int s = (idx >> 4) % 1000;
  int bh = idx / 16000;
  int b = bh >> 3, hd = bh & 7;
  int s0 = undo[bh*4000 + s];
  int s1 = undo[bh*4000 + 1000 + s];
  int s2 = undo[bh*4000 + 2000 + s];
  int s3 = undo[bh*4000 + 3000 + s];
  float l0 = slse[bh*4000 + s0], l1 = slse[bh*4000 + s1];
  float l2 = slse[bh*4000 + s2], l3 = slse[bh*4000 + s3];
  float m = fmaxf(fmaxf(l0,l1), fmaxf(l2,l3));
  float w0 = expf(l0-m), w1 = expf(l1-m), w2 = expf(l2-m), w3 = expf(l3-m);
  float rs = 1.f/(w0+w1+w2+w3);
  const float* base = so + (size_t)bh*4000*16;
  float o = w0*base[s0*16+d] + w1*base[s1*16+d] + w2*base[s2*16+d] + w3*base[s3*16+d];
  ao[((size_t)b*1000 + s)*128 + hd*16 + d] = o * rs;
}

// ---------------- fused PKM (dots + 3x top-16 + softmax + gather) ----------------
__global__ __launch_bounds__(256) void pkm_kernel(
    const float* __restrict__ q, const float* __restrict__ keys,
    const float* __restrict__ values, float* __restrict__ x2out) {
  int row = blockIdx.x;
  int tid = threadIdx.x;
  int w = tid >> 6;       // head 0..3 (one wave each)
  int lane = tid & 63;
  __shared__ float QS[512];
  __shared__ float DOTS[4][2][128];
  __shared__ float SX[4][16], SY[4][16];
  __shared__ int IX[4][16], IY[4][16];
  __shared__ float OUT[4][128];
  QS[tid]       = q[(size_t)row*512 + tid];
  QS[tid + 256] = q[(size_t)row*512 + 256 + tid];
  __syncthreads();
  #pragma unroll
  for (int i = 0; i < 4; ++i) {
    int di = i*64 + lane;
    int p = di >> 7, n = di & 127;
    const float* kr = keys + ((size_t)(w*128 + n)*2 + p)*64;
    const float* qr = QS + w*128 + p*64;
    float acc = 0.f;
    #pragma unroll
    for (int d = 0; d < 64; ++d) acc += qr[d]*kr[d];
    DOTS[w][p][n] = acc;
  }
  __syncthreads();
  // top-16 (descending, lower index wins ties) for p=0 (x) and p=1 (y)
  #pragma unroll
  for (int p = 0; p < 2; ++p) {
    float a0 = DOTS[w][p][lane], a1 = DOTS[w][p][lane + 64];
    int i0 = lane, i1 = lane + 64;
    float tv[16]; int ti[16];
    #pragma unroll
    for (int k = 0; k < 16; ++k) {
      float bv; int bi;
      if (a1 > a0) { bv = a1; bi = i1; } else { bv = a0; bi = i0; }
      #pragma unroll
      for (int o = 32; o > 0; o >>= 1) {
        float ov = __shfl_xor(bv, o);
        int oi = __shfl_xor(bi, o);
        if (ov > bv || (ov == bv && oi < bi)) { bv = ov; bi = oi; }
      }
      tv[k] = bv; ti[k] = bi;
      if (bi == i0) a0 = -INFINITY;
      if (bi == i1) a1 = -INFINITY;
    }
    if (lane == 0) {
      #pragma unroll
      for (int k = 0; k < 16; ++k) {
        if (p == 0) { SX[w][k] = tv[k]; IX[w][k] = ti[k]; }
        else        { SY[w][k] = tv[k]; IY[w][k] = ti[k]; }
      }
    }
    __syncthreads();
  }
  // 256 combos, top-16 with flat-index tie-break
  float cv0 = SX[w][(lane*4+0)>>4] + SY[w][(lane*4+0)&15];
  float cv1 = SX[w][(lane*4+1)>>4] + SY[w][(lane*4+1)&15];
  float cv2 = SX[w][(lane*4+2)>>4] + SY[w][(lane*4+2)&15];
  float cv3 = SX[w][(lane*4+3)>>4] + SY[w][(lane*4+3)&15];
  float fs[16]; int fi[16];
  #pragma unroll
  for (int k = 0; k < 16; ++k) {
    float bv = cv0; int bc = lane*4;
    if (cv1 > bv) { bv = cv1; bc = lane*4+1; }
    if (cv2 > bv) { bv = cv2; bc = lane*4+2; }
    if (cv3 > bv) { bv = cv3; bc = lane*4+3; }
    #pragma unroll
    for (int o = 32; o > 0; o >>= 1) {
      float ov = __shfl_xor(bv, o);
      int oc = __shfl_xor(bc, o);
      if (ov > bv || (ov == bv && oc < bc)) { bv = ov; bc = oc; }
    }
    fs[k] = bv;
    fi[k] = IX[w][bc>>4]*128 + IY[w][bc&15];
    if (bc == lane*4)   cv0 = -INFINITY;
    if (bc == lane*4+1) cv1 = -INFINITY;
    if (bc == lane*4+2) cv2 = -INFINITY;
    if (bc == lane*4+3) cv3 = -INFINITY;
  }
  float wsum = 0.f;
  float wg[16];
  #pragma unroll
  for (int k = 0; k < 16; ++k) { wg[k] = expf(fs[k] - fs[0]); wsum += wg[k]; }
  float rs = 1.f/wsum;
  float o0 = 0.f, o1 = 0.f;
  #pragma unroll
  for (int k = 0; k < 16; ++k) {
    const float* vr = values + (size_t)fi[k]*128;
    float wt = wg[k]*rs;
    o0 += wt * vr[lane];
    o1 += wt * vr[lane+64];
  }
  OUT[w][lane] = o0;
  OUT[w][lane+64] = o1;
  __syncthreads();
  if (tid < 128) {
    float r = OUT[0][tid] + OUT[1][tid] + OUT[2][tid] + OUT[3][tid];
    x2out[(size_t)row*128 + tid] += r;
  }
}

// ---------------- host ----------------
extern "C" void kernel_launch(void* const* d_in, const int* in_sizes, int n_in,
                              void* d_out, int out_size, void* d_ws, size_t ws_size,
                              hipStream_t stream) {
  (void)in_sizes; (void)n_in; (void)out_size; (void)ws_size;
  const int* x_mcc  = (const int*)d_in[0];
  const int* x_amt  = (const int*)d_in[1];
  const int* x_hour = (const int*)d_in[2];
  const int* x_wday = (const int*)d_in[3];
  const float* emb_mcc  = (const float*)d_in[4];
  const float* emb_amt  = (const float*)d_in[5];
  const float* emb_hour = (const float*)d_in[6];
  const float* emb_wday = (const float*)d_in[7];
  const float* rot   = (const float*)d_in[8];
  const float* ln1_g = (const float*)d_in[9];
  const float* ln1_b = (const float*)d_in[10];
  const float* ln2_g = (const float*)d_in[11];
  const float* ln2_b = (const float*)d_in[12];
  const float* Wqk = (const float*)d_in[13];
  const float* Wv  = (const float*)d_in[14];
  const float* Wo  = (const float*)d_in[15];
  const float* bo  = (const float*)d_in[16];
  const float* ff_w1 = (const float*)d_in[17];
  const float* ff_b1 = (const float*)d_in[18];
  const float* ff_w2 = (const float*)d_in[19];
  const float* ff_b2 = (const float*)d_in[20];
  const float* pkm_wq   = (const float*)d_in[21];
  const float* pkm_keys = (const float*)d_in[22];
  const float* pkm_vals = (const float*)d_in[23];
  const float* norm_g = (const float*)d_in[24];
  const float* norm_b = (const float*)d_in[25];
  const float* hw1 = (const float*)d_in[26];
  const float* hb1 = (const float*)d_in[27];

  float* ws = (float*)d_ws;
  float* x1v  = ws;                    // 2,048,000 f
  float* x2v  = ws + 2048000;          // 2,048,000 f
  float* hbuf = ws + 4096000;          // 2,048,000 f
  float* scrA = ws + 6144000;          // 16,384,000 f shared-scratch
  float* qk     = scrA;                //  2,048,000
  float* vv     = scrA + 2048000;      //  2,048,000
  float* so     = scrA + 4096000;      //  8,192,000
  float* slse   = scrA + 12288000;     //    512,000
  int*   buckets= (int*)(scrA + 12800000); // 512,000
  int*   stp    = (int*)(scrA + 13312000); // 512,000
  int*   undo   = (int*)(scrA + 13824000); // 512,000
  float* attn_o = scrA + 14336000;     //  2,048,000
  float* big    = scrA;                //  8,192,000 (FF hidden / PKM q; attention scratch dead by then)

  embed_kernel<<<16000, 128, 0, stream>>>(x_mcc, x_amt, x_hour, x_wday,
      emb_mcc, emb_amt, emb_hour, emb_wday, x1v, x2v);

  int ffi = 0, pki = 0;
  for (int l = 0; l < 8; ++l) {
    ln_kernel<<<16000, 64, 0, stream>>>(x2v, nullptr, ln1_g + l*128, ln1_b + l*128, hbuf);
    { dim3 g(250, 2); matmul_kernel<<<g, 256, 0, stream>>>(hbuf, Wqk + (size_t)l*16384, nullptr, qk, 16000, 128, 128, MM_SPLIT); }
    { dim3 g(250, 2); matmul_kernel<<<g, 256, 0, stream>>>(hbuf, Wv  + (size_t)l*16384, nullptr, vv, 16000, 128, 128, MM_SPLIT); }
    bucket_kernel<<<500, 256, 0, stream>>>(qk, rot, buckets);
    sort_kernel<<<512, 64, 0, stream>>>(buckets, stp, undo);
    attn_chunk_kernel<<<20480, 64, 0, stream>>>(qk, vv, stp, x_mcc, so, slse);
    combine_kernel<<<8000, 256, 0, stream>>>(so, slse, undo, attn_o);
    { dim3 g(250, 2); matmul_kernel<<<g, 256, 0, stream>>>(attn_o, Wo + (size_t)l*16384, bo + l*128, x1v, 16000, 128, 128, MM_RES); }
    ln_kernel<<<16000, 64, 0, stream>>>(x1v, nullptr, ln2_g + l*128, ln2_b + l*128, hbuf);
    if (l == 3 || l == 6) {
      { dim3 g(250, 8); matmul_kernel<<<g, 256, 0, stream>>>(hbuf, pkm_wq + (size_t)pki*65536, nullptr, big, 16000, 512, 128, 0); }
      pkm_kernel<<<16000, 256, 0, stream>>>(big, pkm_keys + (size_t)pki*65536, pkm_vals + (size_t)pki*2097152, x2v);
      ++pki;
    } else {
      { dim3 g(250, 8); matmul_kernel<<<g, 256, 0, stream>>>(hbuf, ff_w1 + (size_t)ffi*65536, ff_b1 + ffi*512, big, 16000, 512, 128, MM_GELU); }
      { dim3 g(250, 2); matmul_kernel<<<g, 256, 0, stream>>>(big, ff_w2 + (size_t)ffi*65536, ff_b2 + ffi*128, x2v, 16000, 128, 512, MM_RES); }
      ++ffi;
    }
  }
  ln_kernel<<<16000, 64, 0, stream>>>(x1v, x2v, norm_g, norm_b, hbuf);

  float* out = (float*)d_out;
  float* hid = scrA;
  const float* w2s[4] = {(const float*)d_in[28], (const float*)d_in[30], (const float*)d_in[32], (const float*)d_in[34]};
  const float* b2s[4] = {(const float*)d_in[29], (const float*)d_in[31], (const float*)d_in[33], (const float*)d_in[35]};
  const int ns[4] = {350, 100, 25, 8};
  size_t ooff = 0;
  for (int i = 0; i < 4; ++i) {
    { dim3 g(250, 2); matmul_kernel<<<g, 256, 0, stream>>>(hbuf, hw1 + (size_t)i*16384, hb1 + i*128, hid, 16000, 128, 128, MM_GELU); }
    { dim3 g(250, (unsigned)((ns[i]+63)/64)); matmul_kernel<<<g, 256, 0, stream>>>(hid, w2s[i], b2s[i], out + ooff, 16000, ns[i], 128, 0); }
    ooff += (size_t)16000 * ns[i];
  }
}

// Round 2
// 5118.784 us; speedup vs baseline: 1.0948x; 1.0948x over previous
//
#include <hip/hip_runtime.h>
#include <math.h>

#define MM_GELU 1
#define MM_RES 2
#define MM_SPLIT 4

// ---------------- embedding + positional encoding ----------------
__global__ __launch_bounds__(128) void embed_kernel(
    const int* __restrict__ xm, const int* __restrict__ xa,
    const int* __restrict__ xh, const int* __restrict__ xw,
    const float* __restrict__ em, const float* __restrict__ ea,
    const float* __restrict__ eh, const float* __restrict__ ew,
    float* __restrict__ x1, float* __restrict__ x2) {
  int row = blockIdx.x;      // 0..15999 = b*1000+s
  int d = threadIdx.x;       // 0..127
  int s = row % 1000;
  float v;
  if (d < 64)       v = em[xm[row]*64 + d];
  else if (d < 96)  v = ea[xa[row]*32 + (d-64)];
  else if (d < 112) v = eh[xh[row]*16 + (d-96)];
  else              v = ew[xw[row]*16 + (d-112)];
  int i = d >> 1;
  float dv = expf((float)(2*i) * (-9.21034037198f/128.f));
  float ang = (float)s * dv;
  v += (d & 1) ? cosf(ang) : sinf(ang);
  x1[row*128 + d] = v;
  x2[row*128 + d] = v;
}

// ---------------- layernorm (optional average of two inputs) ----------------
__global__ __launch_bounds__(64) void ln_kernel(
    const float* __restrict__ x, const float* __restrict__ xb,
    const float* __restrict__ g, const float* __restrict__ b,
    float* __restrict__ out) {
  int row = blockIdx.x;
  int t = threadIdx.x;       // 64 lanes, 2 elems each
  float v0 = x[row*128 + t], v1 = x[row*128 + 64 + t];
  if (xb) { v0 = 0.5f*(v0 + xb[row*128 + t]); v1 = 0.5f*(v1 + xb[row*128 + 64 + t]); }
  float sum = v0 + v1;
  #pragma unroll
  for (int o = 32; o > 0; o >>= 1) sum += __shfl_xor(sum, o);
  float mean = sum * (1.f/128.f);
  float d0 = v0 - mean, d1 = v1 - mean;
  float vs = d0*d0 + d1*d1;
  #pragma unroll
  for (int o = 32; o > 0; o >>= 1) vs += __shfl_xor(vs, o);
  float rstd = rsqrtf(vs*(1.f/128.f) + 1e-5f);
  out[row*128 + t]      = d0*rstd*g[t]    + b[t];
  out[row*128 + 64 + t] = d1*rstd*g[t+64] + b[t+64];
}

// ---------------- generic tiled f32 matmul with fused epilogue ----------------
// C[M,N] (= or +=) act(A[M,K] @ W[K,N] + bias). M % 64 == 0, K % 32 == 0.
__global__ __launch_bounds__(256) void matmul_kernel(
    const float* __restrict__ A, const float* __restrict__ W,
    const float* __restrict__ bias, float* __restrict__ C,
    int M, int N, int K, int flags) {
  __shared__ float As[64][33];
  __shared__ __align__(16) float Bs[32][64];
  int tid = threadIdx.x;
  int bm = blockIdx.x * 64;
  int bn = blockIdx.y * 64;
  int tr = (tid >> 4) * 4;
  int tc = (tid & 15) * 4;
  float acc[4][4];
  #pragma unroll
  for (int i = 0; i < 4; ++i)
    #pragma unroll
    for (int j = 0; j < 4; ++j) acc[i][j] = 0.f;
  for (int k0 = 0; k0 < K; k0 += 32) {
    #pragma unroll
    for (int i = 0; i < 8; ++i) {
      int e = tid + i*256;
      int rr = e >> 5, kk = e & 31;
      As[rr][kk] = A[(size_t)(bm + rr)*K + k0 + kk];
    }
    #pragma unroll
    for (int i = 0; i < 8; ++i) {
      int e = tid + i*256;
      int kk = e >> 6, cc = e & 63;
      int col = bn + cc;
      Bs[kk][cc] = (col < N) ? W[(size_t)(k0 + kk)*N + col] : 0.f;
    }
    __syncthreads();
    #pragma unroll
    for (int kk = 0; kk < 32; ++kk) {
      float a0 = As[tr+0][kk], a1 = As[tr+1][kk], a2 = As[tr+2][kk], a3 = As[tr+3][kk];
      float4 b4 = *(const float4*)&Bs[kk][tc];
      acc[0][0] += a0*b4.x; acc[0][1] += a0*b4.y; acc[0][2] += a0*b4.z; acc[0][3] += a0*b4.w;
      acc[1][0] += a1*b4.x; acc[1][1] += a1*b4.y; acc[1][2] += a1*b4.z; acc[1][3] += a1*b4.w;
      acc[2][0] += a2*b4.x; acc[2][1] += a2*b4.y; acc[2][2] += a2*b4.z; acc[2][3] += a2*b4.w;
      acc[3][0] += a3*b4.x; acc[3][1] += a3*b4.y; acc[3][2] += a3*b4.z; acc[3][3] += a3*b4.w;
    }
    __syncthreads();
  }
  #pragma unroll
  for (int i = 0; i < 4; ++i) {
    int row = bm + tr + i;
    #pragma unroll
    for (int j = 0; j < 4; ++j) {
      int col = bn + tc + j;
      if (col < N) {
        float val = acc[i][j];
        if (bias) val += bias[col];
        if (flags & MM_GELU) val = 0.5f*val*(1.f + erff(val*0.70710678118f));
        size_t oi;
        if (flags & MM_SPLIT) {
          int bb = row / 1000, ss = row % 1000;
          int hd = col >> 4, dd = col & 15;
          oi = (((size_t)(bb*8 + hd))*1000 + ss)*16 + dd;
        } else {
          oi = (size_t)row*N + col;
        }
        if (flags & MM_RES) C[oi] += val; else C[oi] = val;
      }
    }
  }
}

// ---------------- LSH bucket assignment ----------------
__global__ __launch_bounds__(256) void bucket_kernel(
    const float* __restrict__ qk, const float* __restrict__ rot,
    int* __restrict__ buckets) {
  int idx = blockIdx.x*256 + threadIdx.x;   // bh*1000+s
  if (idx >= 128000) return;
  int bh = idx / 1000, s = idx % 1000;
  float q[16];
  #pragma unroll
  for (int d = 0; d < 16; ++d) q[d] = qk[(bh*1000+s)*16 + d];
  #pragma unroll 1
  for (int r = 0; r < 4; ++r) {
    float rv[20];
    #pragma unroll
    for (int n = 0; n < 20; ++n) {
      float acc = 0.f;
      #pragma unroll
      for (int d = 0; d < 16; ++d) acc += q[d]*rot[(d*4 + r)*20 + n];
      rv[n] = acc;
    }
    float best = -INFINITY; int bi = 0;
    #pragma unroll
    for (int n = 0; n < 40; ++n) {
      float val = (n < 20) ? rv[n] : -rv[n-20];
      if (val > best) { best = val; bi = n; }
    }
    buckets[(bh*4 + r)*1000 + s] = bi;
  }
}

// ---------------- stable counting sort per (bh, round) ----------------
__global__ __launch_bounds__(64) void sort_kernel(
    const int* __restrict__ buckets, int* __restrict__ st, int* __restrict__ undo) {
  int bh = blockIdx.x >> 2;
  int r = blockIdx.x & 3;
  const int* bkt = buckets + (bh*4 + r)*1000;
  __shared__ int cnt[40];
  __shared__ int off[40];
  int lane = threadIdx.x;
  if (lane < 40) cnt[lane] = 0;
  __syncthreads();
  for (int s = lane; s < 1000; s += 64) atomicAdd(&cnt[bkt[s]], 1);
  __syncthreads();
  if (lane == 0) {
    int acc = 0;
    for (int bb = 0; bb < 40; ++bb) { off[bb] = acc; acc += cnt[bb]; }
  }
  __syncthreads();
  int base = bh*4000 + r*1000;
  for (int c0 = 0; c0 < 1000; c0 += 64) {
    int s = c0 + lane;
    int b = (s < 1000) ? bkt[s] : -1;
    for (int bb = 0; bb < 40; ++bb) {
      unsigned long long mask = __ballot(b == bb);
      if (mask == 0ull) continue;
      int bo = off[bb];
      if (b == bb) {
        int rank = (int)__popcll(mask & ((1ull << lane) - 1ull));
        int slot = bo + rank;
        st[base + slot] = s;
        undo[base + s] = r*1000 + slot;
      }
      if (lane == 63) off[bb] = bo + (int)__popcll(mask);
      __syncthreads();
    }
  }
}

// ---------------- per-chunk attention (25 q x 50 kv) ----------------
__global__ __launch_bounds__(64) void attn_chunk_kernel(
    const float* __restrict__ qk, const float* __restrict__ v,
    const int* __restrict__ st, const int* __restrict__ xm,
    float* __restrict__ so, float* __restrict__ slse) {
  int blk = blockIdx.x;
  int bh = blk / 160;
  int n = blk % 160;
  int b = bh >> 3;
  int lane = threadIdx.x;
  __shared__ float SQ[25][17], BK[50][17], BV[50][17];
  __shared__ float DOT[25][50];
  __shared__ int TQ[25], TKV[50], MQ[25], MKV[50];
  int pn = (n + 159) % 160;
  if (lane < 50) {
    int slot = (lane < 25) ? (n*25 + lane) : (pn*25 + (lane - 25));
    int t = st[bh*4000 + slot];
    TKV[lane] = t;
    int m = (xm[b*1000 + t] != 0) ? 1 : 0;
    MKV[lane] = m;
    const float* qr = qk + ((size_t)bh*1000 + t)*16;
    const float* vr = v  + ((size_t)bh*1000 + t)*16;
    float ss = 1e-9f;
    float tmp[16];
    #pragma unroll
    for (int d = 0; d < 16; ++d) { tmp[d] = qr[d]; ss += tmp[d]*tmp[d]; }
    float rsq = rsqrtf(ss);
    #pragma unroll
    for (int d = 0; d < 16; ++d) { BK[lane][d] = tmp[d]*rsq; BV[lane][d] = vr[d]; }
    if (lane < 25) {
      TQ[lane] = t; MQ[lane] = m;
      #pragma unroll
      for (int d = 0; d < 16; ++d) SQ[lane][d] = tmp[d];
    }
  }
  __syncthreads();
  for (int p = lane; p < 1250; p += 64) {
    int qi = p / 50, ki = p % 50;
    float acc = 0.f;
    #pragma unroll
    for (int d = 0; d < 16; ++d) acc += SQ[qi][d]*BK[ki][d];
    acc *= 0.25f;
    if (!(MQ[qi] && MKV[ki])) acc = -1e9f;
    int tq = TQ[qi], tk = TKV[ki];
    if (tq < tk) acc = -1e9f;
    if (tq == tk) acc = -5e4f;
    DOT[qi][ki] = acc;
  }
  __syncthreads();
  if (lane < 25) {
    float m = -INFINITY;
    for (int k = 0; k < 50; ++k) m = fmaxf(m, DOT[lane][k]);
    float sum = 0.f;
    for (int k = 0; k < 50; ++k) sum += expf(DOT[lane][k] - m);
    float lse = m + logf(sum);
    float o[16];
    #pragma unroll
    for (int d = 0; d < 16; ++d) o[d] = 0.f;
    for (int k = 0; k < 50; ++k) {
      float wt = expf(DOT[lane][k] - lse);
      #pragma unroll
      for (int d = 0; d < 16; ++d) o[d] += wt * BV[k][d];
    }
    int slot = n*25 + lane;
    float* op = so + ((size_t)bh*4000 + slot)*16;
    #pragma unroll
    for (int d = 0; d < 16; ++d) op[d] = o[d];
    slse[bh*4000 + slot] = lse;
  }
}

// ---------------- unsort + combine hash rounds + merge heads ----------------
__global__ __launch_bounds__(256) void combine_kernel(
    const float* __restrict__ so, const float* __restrict__ slse,
    const int* __restrict__ undo, float* __restrict__ ao) {
  int idx = blockIdx.x*256 + threadIdx.x;
  if (idx >= 2048000) return;
  int d = idx & 15;
  int s = (idx >> 4) % 1000;
  int bh = idx / 16000;
  int b = bh >> 3, hd = bh & 7;
  int s0 = undo[bh*4000 + s];
  int s1 = undo[bh*4000 + 1000 + s];
  int s2 = undo[bh*4000 + 2000 + s];
  int s3 = undo[bh*4000 + 3000 + s];
  float l0 = slse[bh*4000 + s0], l1 = slse[bh*4000 + s1];
  float l2 = slse[bh*4000 + s2], l3 = slse[bh*4000 + s3];
  float m = fmaxf(fmaxf(l0,l1), fmaxf(l2,l3));
  float w0 = expf(l0-m), w1 = expf(l1-m), w2 = expf(l2-m), w3 = expf(l3-m);
  float rs = 1.f/(w0+w1+w2+w3);
  const float* base = so + (size_t)bh*4000*16;
  float o = w0*base[s0*16+d] + w1*base[s1*16+d] + w2*base[s2*16+d] + w3*base[s3*16+d];
  ao[((size_t)b*1000 + s)*128 + hd*16 + d] = o * rs;
}

// ---------------- PKM prep: M[k, (h,p,n)] = sum_d Wq[k, h*128+p*64+d] * keys[h,n,p,d] ----------------
__global__ __launch_bounds__(256) void pkm_m_kernel(
    const float* __restrict__ Wq, const float* __restrict__ keys,
    float* __restrict__ M) {
  int hp = blockIdx.x;          // 0..7 = h*2+p
  int h = hp >> 1, p = hp & 1;
  int tid = threadIdx.x;
  __shared__ float Ks[128][65];
  for (int e = tid; e < 8192; e += 256) {
    int n = e >> 6, d = e & 63;
    Ks[n][d] = keys[((size_t)(h*128 + n)*2 + p)*64 + d];
  }
  __syncthreads();
  int k = tid >> 1;
  int nbase = (tid & 1) * 64;
  float wk[64];
  const float* wq = Wq + (size_t)k*512 + h*128 + p*64;
  #pragma unroll
  for (int d = 0; d < 64; ++d) wk[d] = wq[d];
  for (int n = 0; n < 64; ++n) {
    int nn = nbase + n;
    float acc = 0.f;
    #pragma unroll
    for (int d = 0; d < 64; ++d) acc += wk[d]*Ks[nn][d];
    M[(size_t)k*1024 + hp*128 + nn] = acc;
  }
}

// ---------------- PKM select: top-16 x/y, 256 combos top-16, softmax, gather ----------------
__global__ __launch_bounds__(256) void pkm_select_kernel(
    const float* __restrict__ dots, const float* __restrict__ values,
    float* __restrict__ x2out) {
  int row = blockIdx.x;
  int tid = threadIdx.x;
  int w = tid >> 6;       // head 0..3 (one wave each)
  int lane = tid & 63;
  __shared__ float SX[4][16], SY[4][16];
  __shared__ int IX[4][16], IY[4][16];
  __shared__ float OUT[4][128];
  const float* dr = dots + (size_t)row*1024 + w*256;
  // top-16 (descending, lower index wins ties) for p=0 (x) and p=1 (y)
  #pragma unroll 1
  for (int p = 0; p < 2; ++p) {
    float a0 = dr[p*128 + lane], a1 = dr[p*128 + 64 + lane];
    int i0 = lane, i1 = lane + 64;
    float tv[16]; int ti[16];
    #pragma unroll
    for (int k = 0; k < 16; ++k) {
      float bv; int bi;
      if (a1 > a0) { bv = a1; bi = i1; } else { bv = a0; bi = i0; }
      #pragma unroll
      for (int o = 32; o > 0; o >>= 1) {
        float ov = __shfl_xor(bv, o);
        int oi = __shfl_xor(bi, o);
        if (ov > bv || (ov == bv && oi < bi)) { bv = ov; bi = oi; }
      }
      tv[k] = bv; ti[k] = bi;
      if (bi == i0) a0 = -INFINITY;
      if (bi == i1) a1 = -INFINITY;
    }
    if (lane == 0) {
      #pragma unroll
      for (int k = 0; k < 16; ++k) {
        if (p == 0) { SX[w][k] = tv[k]; IX[w][k] = ti[k]; }
        else        { SY[w][k] = tv[k]; IY[w][k] = ti[k]; }
      }
    }
  }
  __syncthreads();
  // 256 combos, top-16 with flat-index tie-break
  float cv0 = SX[w][(lane*4+0)>>4] + SY[w][(lane*4+0)&15];
  float cv1 = SX[w][(lane*4+1)>>4] + SY[w][(lane*4+1)&15];
  float cv2 = SX[w][(lane*4+2)>>4] + SY[w][(lane*4+2)&15];
  float cv3 = SX[w][(lane*4+3)>>4] + SY[w][(lane*4+3)&15];
  float fs[16]; int fi[16];
  #pragma unroll
  for (int k = 0; k < 16; ++k) {
    float bv = cv0; int bc = lane*4;
    if (cv1 > bv) { bv = cv1; bc = lane*4+1; }
    if (cv2 > bv) { bv = cv2; bc = lane*4+2; }
    if (cv3 > bv) { bv = cv3; bc = lane*4+3; }
    #pragma unroll
    for (int o = 32; o > 0; o >>= 1) {
      float ov = __shfl_xor(bv, o);
      int oc = __shfl_xor(bc, o);
      if (ov > bv || (ov == bv && oc < bc)) { bv = ov; bc = oc; }
    }
    fs[k] = bv;
    fi[k] = IX[w][bc>>4]*128 + IY[w][bc&15];
    if (bc == lane*4)   cv0 = -INFINITY;
    if (bc == lane*4+1) cv1 = -INFINITY;
    if (bc == lane*4+2) cv2 = -INFINITY;
    if (bc == lane*4+3) cv3 = -INFINITY;
  }
  float wsum = 0.f;
  float wg[16];
  #pragma unroll
  for (int k = 0; k < 16; ++k) { wg[k] = expf(fs[k] - fs[0]); wsum += wg[k]; }
  float rs = 1.f/wsum;
  float o0 = 0.f, o1 = 0.f;
  #pragma unroll
  for (int k = 0; k < 16; ++k) {
    const float* vr = values + (size_t)fi[k]*128;
    float wt = wg[k]*rs;
    o0 += wt * vr[lane];
    o1 += wt * vr[lane+64];
  }
  OUT[w][lane] = o0;
  OUT[w][lane+64] = o1;
  __syncthreads();
  if (tid < 128) {
    float r = OUT[0][tid] + OUT[1][tid] + OUT[2][tid] + OUT[3][tid];
    x2out[(size_t)row*128 + tid] += r;
  }
}

// ---------------- host ----------------
extern "C" void kernel_launch(void* const* d_in, const int* in_sizes, int n_in,
                              void* d_out, int out_size, void* d_ws, size_t ws_size,
                              hipStream_t stream) {
  (void)in_sizes; (void)n_in; (void)out_size; (void)ws_size;
  const int* x_mcc  = (const int*)d_in[0];
  const int* x_amt  = (const int*)d_in[1];
  const int* x_hour = (const int*)d_in[2];
  const int* x_wday = (const int*)d_in[3];
  const float* emb_mcc  = (const float*)d_in[4];
  const float* emb_amt  = (const float*)d_in[5];
  const float* emb_hour = (const float*)d_in[6];
  const float* emb_wday = (const float*)d_in[7];
  const float* rot   = (const float*)d_in[8];
  const float* ln1_g = (const float*)d_in[9];
  const float* ln1_b = (const float*)d_in[10];
  const float* ln2_g = (const float*)d_in[11];
  const float* ln2_b = (const float*)d_in[12];
  const float* Wqk = (const float*)d_in[13];
  const float* Wv  = (const float*)d_in[14];
  const float* Wo  = (const float*)d_in[15];
  const float* bo  = (const float*)d_in[16];
  const float* ff_w1 = (const float*)d_in[17];
  const float* ff_b1 = (const float*)d_in[18];
  const float* ff_w2 = (const float*)d_in[19];
  const float* ff_b2 = (const float*)d_in[20];
  const float* pkm_wq   = (const float*)d_in[21];
  const float* pkm_keys = (const float*)d_in[22];
  const float* pkm_vals = (const float*)d_in[23];
  const float* norm_g = (const float*)d_in[24];
  const float* norm_b = (const float*)d_in[25];
  const float* hw1 = (const float*)d_in[26];
  const float* hb1 = (const float*)d_in[27];

  float* ws = (float*)d_ws;
  float* x1v  = ws;                    // 2,048,000 f
  float* x2v  = ws + 2048000;          // 2,048,000 f
  float* hbuf = ws + 4096000;          // 2,048,000 f
  float* scrA = ws + 6144000;          // 16,384,000 f shared-scratch
  float* qk     = scrA;                //  2,048,000
  float* vv     = scrA + 2048000;      //  2,048,000
  float* so     = scrA + 4096000;      //  8,192,000
  float* slse   = scrA + 12288000;     //    512,000
  int*   buckets= (int*)(scrA + 12800000); // 512,000
  int*   stp    = (int*)(scrA + 13312000); // 512,000
  int*   undo   = (int*)(scrA + 13824000); // 512,000
  float* attn_o = scrA + 14336000;     //  2,048,000
  float* big    = scrA;                //  8,192,000 (FF hidden; attention scratch dead by then)
  float* dotsb  = scrA;                // 16,384,000 (PKM dots [16000,1024]; attn scratch dead)
  float* Mbuf   = ws + 22528000;       //    131,072 (PKM fused dot matrix, per layer)

  embed_kernel<<<16000, 128, 0, stream>>>(x_mcc, x_amt, x_hour, x_wday,
      emb_mcc, emb_amt, emb_hour, emb_wday, x1v, x2v);

  int ffi = 0, pki = 0;
  for (int l = 0; l < 8; ++l) {
    ln_kernel<<<16000, 64, 0, stream>>>(x2v, nullptr, ln1_g + l*128, ln1_b + l*128, hbuf);
    { dim3 g(250, 2); matmul_kernel<<<g, 256, 0, stream>>>(hbuf, Wqk + (size_t)l*16384, nullptr, qk, 16000, 128, 128, MM_SPLIT); }
    { dim3 g(250, 2); matmul_kernel<<<g, 256, 0, stream>>>(hbuf, Wv  + (size_t)l*16384, nullptr, vv, 16000, 128, 128, MM_SPLIT); }
    bucket_kernel<<<500, 256, 0, stream>>>(qk, rot, buckets);
    sort_kernel<<<512, 64, 0, stream>>>(buckets, stp, undo);
    attn_chunk_kernel<<<20480, 64, 0, stream>>>(qk, vv, stp, x_mcc, so, slse);
    combine_kernel<<<8000, 256, 0, stream>>>(so, slse, undo, attn_o);
    { dim3 g(250, 2); matmul_kernel<<<g, 256, 0, stream>>>(attn_o, Wo + (size_t)l*16384, bo + l*128, x1v, 16000, 128, 128, MM_RES); }
    ln_kernel<<<16000, 64, 0, stream>>>(x1v, nullptr, ln2_g + l*128, ln2_b + l*128, hbuf);
    if (l == 3 || l == 6) {
      pkm_m_kernel<<<8, 256, 0, stream>>>(pkm_wq + (size_t)pki*65536, pkm_keys + (size_t)pki*65536, Mbuf);
      { dim3 g(250, 16); matmul_kernel<<<g, 256, 0, stream>>>(hbuf, Mbuf, nullptr, dotsb, 16000, 1024, 128, 0); }
      pkm_select_kernel<<<16000, 256, 0, stream>>>(dotsb, pkm_vals + (size_t)pki*2097152, x2v);
      ++pki;
    } else {
      { dim3 g(250, 8); matmul_kernel<<<g, 256, 0, stream>>>(hbuf, ff_w1 + (size_t)ffi*65536, ff_b1 + ffi*512, big, 16000, 512, 128, MM_GELU); }
      { dim3 g(250, 2); matmul_kernel<<<g, 256, 0, stream>>>(big, ff_w2 + (size_t)ffi*65536, ff_b2 + ffi*128, x2v, 16000, 128, 512, MM_RES); }
      ++ffi;
    }
  }
  ln_kernel<<<16000, 64, 0, stream>>>(x1v, x2v, norm_g, norm_b, hbuf);

  float* out = (float*)d_out;
  float* hid = scrA;
  const float* w2s[4] = {(const float*)d_in[28], (const float*)d_in[30], (const float*)d_in[32], (const float*)d_in[34]};
  const float* b2s[4] = {(const float*)d_in[29], (const float*)d_in[31], (const float*)d_in[33], (const float*)d_in[35]};
  const int ns[4] = {350, 100, 25, 8};
  size_t ooff = 0;
  for (int i = 0; i < 4; ++i) {
    { dim3 g(250, 2); matmul_kernel<<<g, 256, 0, stream>>>(hbuf, hw1 + (size_t)i*16384, hb1 + i*128, hid, 16000, 128, 128, MM_GELU); }
    { dim3 g(250, (unsigned)((ns[i]+63)/64)); matmul_kernel<<<g, 256, 0, stream>>>(hid, w2s[i], b2s[i], out + ooff, 16000, ns[i], 128, 0); }
    ooff += (size_t)16000 * ns[i];
  }
}

// Round 4
// 3706.866 us; speedup vs baseline: 1.5117x; 1.3809x over previous
//
#include <hip/hip_runtime.h>
#include <math.h>

#define MM_GELU 1
#define MM_RES 2
#define MM_SPLIT 4

typedef __attribute__((ext_vector_type(8))) short bfrag;
typedef __attribute__((ext_vector_type(4))) float f32x4;

__device__ inline unsigned short f2bf_rne(float f) {
  unsigned u = __float_as_uint(f);
  unsigned r = u + 0x7FFFu + ((u >> 16) & 1u);
  return (unsigned short)(r >> 16);
}
__device__ inline float bf2f(unsigned short h) {
  return __uint_as_float(((unsigned)h) << 16);
}

// ---------------- embedding + positional encoding ----------------
__global__ __launch_bounds__(128) void embed_kernel(
    const int* __restrict__ xm, const int* __restrict__ xa,
    const int* __restrict__ xh, const int* __restrict__ xw,
    const float* __restrict__ em, const float* __restrict__ ea,
    const float* __restrict__ eh, const float* __restrict__ ew,
    float* __restrict__ x1, float* __restrict__ x2) {
  int row = blockIdx.x;
  int d = threadIdx.x;
  int s = row % 1000;
  float v;
  if (d < 64)       v = em[xm[row]*64 + d];
  else if (d < 96)  v = ea[xa[row]*32 + (d-64)];
  else if (d < 112) v = eh[xh[row]*16 + (d-96)];
  else              v = ew[xw[row]*16 + (d-112)];
  int i = d >> 1;
  float dv = expf((float)(2*i) * (-9.21034037198f/128.f));
  float ang = (float)s * dv;
  v += (d & 1) ? cosf(ang) : sinf(ang);
  x1[row*128 + d] = v;
  x2[row*128 + d] = v;
}

// ---------------- layernorm ----------------
__global__ __launch_bounds__(64) void ln_kernel(
    const float* __restrict__ x, const float* __restrict__ xb,
    const float* __restrict__ g, const float* __restrict__ b,
    float* __restrict__ out) {
  int row = blockIdx.x;
  int t = threadIdx.x;
  float v0 = x[row*128 + t], v1 = x[row*128 + 64 + t];
  if (xb) { v0 = 0.5f*(v0 + xb[row*128 + t]); v1 = 0.5f*(v1 + xb[row*128 + 64 + t]); }
  float sum = v0 + v1;
  #pragma unroll
  for (int o = 32; o > 0; o >>= 1) sum += __shfl_xor(sum, o);
  float mean = sum * (1.f/128.f);
  float d0 = v0 - mean, d1 = v1 - mean;
  float vs = d0*d0 + d1*d1;
  #pragma unroll
  for (int o = 32; o > 0; o >>= 1) vs += __shfl_xor(vs, o);
  float rstd = rsqrtf(vs*(1.f/128.f) + 1e-5f);
  out[row*128 + t]      = d0*rstd*g[t]    + b[t];
  out[row*128 + 64 + t] = d1*rstd*g[t+64] + b[t+64];
}

// ---------------- MFMA bf16x3 matmul: C = act(A[M,K] @ W[K,N] + bias) ----------------
// Tile 64x64, 4 waves; wave w owns rows [w*16, w*16+16). bf16x3 split => ~f32 accuracy.
__global__ __launch_bounds__(256) void mfma_matmul_kernel(
    const float* __restrict__ A, const float* __restrict__ W,
    const float* __restrict__ bias, float* __restrict__ C,
    int M, int N, int K, int flags) {
  __shared__ __align__(16) unsigned short Ah[64*40], Al[64*40], Bh[64*40], Bl[64*40];
  int tid = threadIdx.x;
  int bm = blockIdx.x * 64, bn = blockIdx.y * 64;
  int w = tid >> 6, lane = tid & 63;
  int l15 = lane & 15, kg = lane >> 4;
  f32x4 acc[4];
  #pragma unroll
  for (int t = 0; t < 4; ++t) { acc[t][0]=0.f; acc[t][1]=0.f; acc[t][2]=0.f; acc[t][3]=0.f; }
  int arr = tid >> 2, akc = (tid & 3) * 8;       // A staging: row, k-offset
  int bcol = tid >> 2, bk0 = (tid & 3) * 8;      // B staging: col, k-offset

  for (int k0 = 0; k0 < K; k0 += 32) {
    // ---- stage A (f32 -> bf16 hi/lo), vectorized global read ----
    {
      const float* ap = A + (size_t)(bm + arr) * K + k0 + akc;
      float4 fa = *(const float4*)(ap);
      float4 fb = *(const float4*)(ap + 4);
      float av8[8] = {fa.x, fa.y, fa.z, fa.w, fb.x, fb.y, fb.z, fb.w};
      bfrag vh, vl;
      #pragma unroll
      for (int j = 0; j < 8; ++j) {
        unsigned short h = f2bf_rne(av8[j]);
        vh[j] = (short)h;
        vl[j] = (short)f2bf_rne(av8[j] - bf2f(h));
      }
      *(bfrag*)&Ah[arr*40 + akc] = vh;
      *(bfrag*)&Al[arr*40 + akc] = vl;
    }
    // ---- stage B transposed: Bh[n][k], scalar global reads (8 k's for one col) ----
    {
      int c = bn + bcol;
      float bv8[8];
      #pragma unroll
      for (int j = 0; j < 8; ++j) {
        int kk = k0 + bk0 + j;
        bv8[j] = (c < N) ? W[(size_t)kk * N + c] : 0.f;
      }
      #pragma unroll
      for (int j = 0; j < 8; j += 2) {
        unsigned short h0 = f2bf_rne(bv8[j]),   h1 = f2bf_rne(bv8[j+1]);
        unsigned short l0 = f2bf_rne(bv8[j]   - bf2f(h0));
        unsigned short l1 = f2bf_rne(bv8[j+1] - bf2f(h1));
        *(unsigned*)&Bh[bcol*40 + bk0 + j] = ((unsigned)h1 << 16) | h0;
        *(unsigned*)&Bl[bcol*40 + bk0 + j] = ((unsigned)l1 << 16) | l0;
      }
    }
    __syncthreads();
    // ---- compute ----
    int am = w*16 + l15;
    bfrag a_h = *(const bfrag*)&Ah[am*40 + kg*8];
    bfrag a_l = *(const bfrag*)&Al[am*40 + kg*8];
    #pragma unroll
    for (int t = 0; t < 4; ++t) {
      int nn = t*16 + l15;
      bfrag b_h = *(const bfrag*)&Bh[nn*40 + kg*8];
      bfrag b_l = *(const bfrag*)&Bl[nn*40 + kg*8];
      acc[t] = __builtin_amdgcn_mfma_f32_16x16x32_bf16(a_h, b_h, acc[t], 0, 0, 0);
      acc[t] = __builtin_amdgcn_mfma_f32_16x16x32_bf16(a_h, b_l, acc[t], 0, 0, 0);
      acc[t] = __builtin_amdgcn_mfma_f32_16x16x32_bf16(a_l, b_h, acc[t], 0, 0, 0);
    }
    __syncthreads();
  }
  // ---- epilogue ----
  #pragma unroll
  for (int t = 0; t < 4; ++t) {
    int col = bn + t*16 + l15;
    if (col < N) {
      #pragma unroll
      for (int r = 0; r < 4; ++r) {
        int row = bm + w*16 + kg*4 + r;
        float val = acc[t][r];
        if (bias) val += bias[col];
        if (flags & MM_GELU) val = 0.5f*val*(1.f + erff(val*0.70710678118f));
        size_t oi;
        if (flags & MM_SPLIT) {
          int bb = row / 1000, ss = row % 1000;
          int hd = col >> 4, dd = col & 15;
          oi = (((size_t)(bb*8 + hd))*1000 + ss)*16 + dd;
        } else {
          oi = (size_t)row*N + col;
        }
        if (flags & MM_RES) C[oi] += val; else C[oi] = val;
      }
    }
  }
}

// ---------------- LSH bucket assignment ----------------
__global__ __launch_bounds__(256) void bucket_kernel(
    const float* __restrict__ qk, const float* __restrict__ rot,
    int* __restrict__ buckets) {
  int idx = blockIdx.x*256 + threadIdx.x;
  if (idx >= 128000) return;
  int bh = idx / 1000, s = idx % 1000;
  float q[16];
  #pragma unroll
  for (int d = 0; d < 16; ++d) q[d] = qk[(bh*1000+s)*16 + d];
  #pragma unroll 1
  for (int r = 0; r < 4; ++r) {
    float rv[20];
    #pragma unroll
    for (int n = 0; n < 20; ++n) {
      float acc = 0.f;
      #pragma unroll
      for (int d = 0; d < 16; ++d) acc += q[d]*rot[(d*4 + r)*20 + n];
      rv[n] = acc;
    }
    float best = -INFINITY; int bi = 0;
    #pragma unroll
    for (int n = 0; n < 40; ++n) {
      float val = (n < 20) ? rv[n] : -rv[n-20];
      if (val > best) { best = val; bi = n; }
    }
    buckets[(bh*4 + r)*1000 + s] = bi;
  }
}

// ---------------- stable counting sort per (bh, round) ----------------
__global__ __launch_bounds__(64) void sort_kernel(
    const int* __restrict__ buckets, int* __restrict__ st, int* __restrict__ undo) {
  int bh = blockIdx.x >> 2;
  int r = blockIdx.x & 3;
  const int* bkt = buckets + (bh*4 + r)*1000;
  __shared__ int cnt[40];
  __shared__ int off[40];
  int lane = threadIdx.x;
  if (lane < 40) cnt[lane] = 0;
  __syncthreads();
  for (int s = lane; s < 1000; s += 64) atomicAdd(&cnt[bkt[s]], 1);
  __syncthreads();
  if (lane == 0) {
    int acc = 0;
    for (int bb = 0; bb < 40; ++bb) { off[bb] = acc; acc += cnt[bb]; }
  }
  __syncthreads();
  int base = bh*4000 + r*1000;
  for (int c0 = 0; c0 < 1000; c0 += 64) {
    int s = c0 + lane;
    int b = (s < 1000) ? bkt[s] : -1;
    for (int bb = 0; bb < 40; ++bb) {
      unsigned long long mask = __ballot(b == bb);
      if (mask == 0ull) continue;
      int bo = off[bb];
      if (b == bb) {
        int rank = (int)__popcll(mask & ((1ull << lane) - 1ull));
        int slot = bo + rank;
        st[base + slot] = s;
        undo[base + s] = r*1000 + slot;
      }
      if (lane == 63) off[bb] = bo + (int)__popcll(mask);
      __syncthreads();
    }
  }
}

// ---------------- per-chunk attention (25 q x 50 kv) ----------------
__global__ __launch_bounds__(64) void attn_chunk_kernel(
    const float* __restrict__ qk, const float* __restrict__ v,
    const int* __restrict__ st, const int* __restrict__ xm,
    float* __restrict__ so, float* __restrict__ slse) {
  int blk = blockIdx.x;
  int bh = blk / 160;
  int n = blk % 160;
  int b = bh >> 3;
  int lane = threadIdx.x;
  __shared__ float SQ[25][17], BK[50][17], BV[50][17];
  __shared__ float DOT[25][50];
  __shared__ int TQ[25], TKV[50], MQ[25], MKV[50];
  int pn = (n + 159) % 160;
  if (lane < 50) {
    int slot = (lane < 25) ? (n*25 + lane) : (pn*25 + (lane - 25));
    int t = st[bh*4000 + slot];
    TKV[lane] = t;
    int m = (xm[b*1000 + t] != 0) ? 1 : 0;
    MKV[lane] = m;
    const float* qr = qk + ((size_t)bh*1000 + t)*16;
    const float* vr = v  + ((size_t)bh*1000 + t)*16;
    float ss = 1e-9f;
    float tmp[16];
    #pragma unroll
    for (int d = 0; d < 16; ++d) { tmp[d] = qr[d]; ss += tmp[d]*tmp[d]; }
    float rsq = rsqrtf(ss);
    #pragma unroll
    for (int d = 0; d < 16; ++d) { BK[lane][d] = tmp[d]*rsq; BV[lane][d] = vr[d]; }
    if (lane < 25) {
      TQ[lane] = t; MQ[lane] = m;
      #pragma unroll
      for (int d = 0; d < 16; ++d) SQ[lane][d] = tmp[d];
    }
  }
  __syncthreads();
  for (int p = lane; p < 1250; p += 64) {
    int qi = p / 50, ki = p % 50;
    float acc = 0.f;
    #pragma unroll
    for (int d = 0; d < 16; ++d) acc += SQ[qi][d]*BK[ki][d];
    acc *= 0.25f;
    if (!(MQ[qi] && MKV[ki])) acc = -1e9f;
    int tq = TQ[qi], tk = TKV[ki];
    if (tq < tk) acc = -1e9f;
    if (tq == tk) acc = -5e4f;
    DOT[qi][ki] = acc;
  }
  __syncthreads();
  if (lane < 25) {
    float m = -INFINITY;
    for (int k = 0; k < 50; ++k) m = fmaxf(m, DOT[lane][k]);
    float sum = 0.f;
    for (int k = 0; k < 50; ++k) sum += expf(DOT[lane][k] - m);
    float lse = m + logf(sum);
    float o[16];
    #pragma unroll
    for (int d = 0; d < 16; ++d) o[d] = 0.f;
    for (int k = 0; k < 50; ++k) {
      float wt = expf(DOT[lane][k] - lse);
      #pragma unroll
      for (int d = 0; d < 16; ++d) o[d] += wt * BV[k][d];
    }
    int slot = n*25 + lane;
    float* op = so + ((size_t)bh*4000 + slot)*16;
    #pragma unroll
    for (int d = 0; d < 16; ++d) op[d] = o[d];
    slse[bh*4000 + slot] = lse;
  }
}

// ---------------- unsort + combine hash rounds + merge heads ----------------
__global__ __launch_bounds__(256) void combine_kernel(
    const float* __restrict__ so, const float* __restrict__ slse,
    const int* __restrict__ undo, float* __restrict__ ao) {
  int idx = blockIdx.x*256 + threadIdx.x;
  if (idx >= 2048000) return;
  int d = idx & 15;
  int s = (idx >> 4) % 1000;
  int bh = idx / 16000;
  int b = bh >> 3, hd = bh & 7;
  int s0 = undo[bh*4000 + s];
  int s1 = undo[bh*4000 + 1000 + s];
  int s2 = undo[bh*4000 + 2000 + s];
  int s3 = undo[bh*4000 + 3000 + s];
  float l0 = slse[bh*4000 + s0], l1 = slse[bh*4000 + s1];
  float l2 = slse[bh*4000 + s2], l3 = slse[bh*4000 + s3];
  float m = fmaxf(fmaxf(l0,l1), fmaxf(l2,l3));
  float w0 = expf(l0-m), w1 = expf(l1-m), w2 = expf(l2-m), w3 = expf(l3-m);
  float rs = 1.f/(w0+w1+w2+w3);
  const float* base = so + (size_t)bh*4000*16;
  float o = w0*base[s0*16+d] + w1*base[s1*16+d] + w2*base[s2*16+d] + w3*base[s3*16+d];
  ao[((size_t)b*1000 + s)*128 + hd*16 + d] = o * rs;
}

// ---------------- PKM prep: M[k, (h,p,n)] ----------------
__global__ __launch_bounds__(256) void pkm_m_kernel(
    const float* __restrict__ Wq, const float* __restrict__ keys,
    float* __restrict__ M) {
  int hp = blockIdx.x;
  int h = hp >> 1, p = hp & 1;
  int tid = threadIdx.x;
  __shared__ float Ks[128][65];
  for (int e = tid; e < 8192; e += 256) {
    int n = e >> 6, d = e & 63;
    Ks[n][d] = keys[((size_t)(h*128 + n)*2 + p)*64 + d];
  }
  __syncthreads();
  int k = tid >> 1;
  int nbase = (tid & 1) * 64;
  float wk[64];
  const float* wq = Wq + (size_t)k*512 + h*128 + p*64;
  #pragma unroll
  for (int d = 0; d < 64; ++d) wk[d] = wq[d];
  for (int n = 0; n < 64; ++n) {
    int nn = nbase + n;
    float acc = 0.f;
    #pragma unroll
    for (int d = 0; d < 64; ++d) acc += wk[d]*Ks[nn][d];
    M[(size_t)k*1024 + hp*128 + nn] = acc;
  }
}

// ---------------- PKM select: bitonic sorts + staircase candidates ----------------
__device__ inline unsigned long long pk_key(float v, int idx) {
  unsigned u = __float_as_uint(v);
  u = (u & 0x80000000u) ? ~u : (u | 0x80000000u);  // mono-increasing with v
  unsigned kv = ~u;                                 // ascending key = descending v
  return ((unsigned long long)kv << 32) | (unsigned)idx;
}
__device__ inline float pk_val(unsigned long long key) {
  unsigned m = ~(unsigned)(key >> 32);
  return (m & 0x80000000u) ? __uint_as_float(m & 0x7FFFFFFFu) : __uint_as_float(~m);
}

__global__ __launch_bounds__(256) void pkm_select_kernel(
    const float* __restrict__ dots, const float* __restrict__ values,
    float* __restrict__ x2out) {
  int row = blockIdx.x;
  int tid = threadIdx.x;
  int w = tid >> 6;
  int lane = tid & 63;
  __shared__ float SVAL[4][2][16];
  __shared__ int SIDX[4][2][16];
  __shared__ float OUT[4][128];
  const float* dr = dots + (size_t)row*1024 + w*256;
  // ---- top-16 of 128 for p=0 (x) and p=1 (y): full bitonic sort, 2 elems/lane ----
  #pragma unroll 1
  for (int p = 0; p < 2; ++p) {
    unsigned long long k0 = pk_key(dr[p*128 + lane], lane);
    unsigned long long k1 = pk_key(dr[p*128 + 64 + lane], 64 + lane);
    #pragma unroll 1
    for (int k = 2; k <= 128; k <<= 1) {
      #pragma unroll 1
      for (int j = k >> 1; j >= 1; j >>= 1) {
        if (j == 64) {
          // e0 (=lane) ascending keep-min vs e1 (=lane+64), local
          unsigned long long lo = (k0 < k1) ? k0 : k1;
          unsigned long long hi = (k0 < k1) ? k1 : k0;
          k0 = lo; k1 = hi;
        } else {
          unsigned long long p0 = __shfl_xor(k0, j);
          unsigned long long p1 = __shfl_xor(k1, j);
          bool low = ((lane & j) == 0);
          bool up0 = ((lane & k) == 0);
          bool up1 = (((lane + 64) & k) == 0);
          bool t0 = (low == up0) ? (p0 < k0) : (p0 > k0);
          bool t1 = (low == up1) ? (p1 < k1) : (p1 > k1);
          if (t0) k0 = p0;
          if (t1) k1 = p1;
        }
      }
    }
    if (lane < 16) {
      SVAL[w][p][lane] = pk_val(k0);
      SIDX[w][p][lane] = (int)(unsigned)(k0 & 0xFFFFFFFFull);
    }
  }
  __syncthreads();
  // ---- 256-combo top-16: only the 50 staircase candidates (kx+1)(ky+1)<=16 ----
  int kx, ky;
  if      (lane < 16) { kx = 0; ky = lane; }
  else if (lane < 24) { kx = 1; ky = lane - 16; }
  else if (lane < 29) { kx = 2; ky = lane - 24; }
  else if (lane < 33) { kx = 3; ky = lane - 29; }
  else if (lane < 36) { kx = 4; ky = lane - 33; }
  else if (lane < 38) { kx = 5; ky = lane - 36; }
  else if (lane < 40) { kx = 6; ky = lane - 38; }
  else if (lane < 42) { kx = 7; ky = lane - 40; }
  else                { kx = 8 + (lane - 42); ky = 0; }
  unsigned long long key;
  if (lane < 50) {
    float cv = SVAL[w][0][kx] + SVAL[w][1][ky];
    key = pk_key(cv, kx*16 + ky);
  } else {
    key = ~0ull;
  }
  #pragma unroll 1
  for (int k = 2; k <= 64; k <<= 1) {
    #pragma unroll 1
    for (int j = k >> 1; j >= 1; j >>= 1) {
      unsigned long long pk = __shfl_xor(key, j);
      bool low = ((lane & j) == 0);
      bool up = ((lane & k) == 0);
      bool take = (low == up) ? (pk < key) : (pk > key);
      if (take) key = pk;
    }
  }
  // lane q holds rank-q combo; decode, softmax in rank order, gather values
  float myv = pk_val(key);
  int pos = (int)(key & 0xFFull);
  int myfi = SIDX[w][0][pos >> 4] * 128 + SIDX[w][1][pos & 15];
  float fs0 = __shfl(myv, 0);
  float osum0 = 0.f, osum1 = 0.f, wsum = 0.f;
  #pragma unroll
  for (int k = 0; k < 16; ++k) {
    float fv = __shfl(myv, k);
    int fik = __shfl(myfi, k);
    float wgk = expf(fv - fs0);
    wsum += wgk;
    const float* vr = values + (size_t)fik * 128;
    osum0 += wgk * vr[lane];
    osum1 += wgk * vr[lane + 64];
  }
  float rs = 1.f / wsum;
  OUT[w][lane] = osum0 * rs;
  OUT[w][lane + 64] = osum1 * rs;
  __syncthreads();
  if (tid < 128) {
    float r = OUT[0][tid] + OUT[1][tid] + OUT[2][tid] + OUT[3][tid];
    x2out[(size_t)row*128 + tid] += r;
  }
}

// ---------------- host ----------------
extern "C" void kernel_launch(void* const* d_in, const int* in_sizes, int n_in,
                              void* d_out, int out_size, void* d_ws, size_t ws_size,
                              hipStream_t stream) {
  (void)in_sizes; (void)n_in; (void)out_size; (void)ws_size;
  const int* x_mcc  = (const int*)d_in[0];
  const int* x_amt  = (const int*)d_in[1];
  const int* x_hour = (const int*)d_in[2];
  const int* x_wday = (const int*)d_in[3];
  const float* emb_mcc  = (const float*)d_in[4];
  const float* emb_amt  = (const float*)d_in[5];
  const float* emb_hour = (const float*)d_in[6];
  const float* emb_wday = (const float*)d_in[7];
  const float* rot   = (const float*)d_in[8];
  const float* ln1_g = (const float*)d_in[9];
  const float* ln1_b = (const float*)d_in[10];
  const float* ln2_g = (const float*)d_in[11];
  const float* ln2_b = (const float*)d_in[12];
  const float* Wqk = (const float*)d_in[13];
  const float* Wv  = (const float*)d_in[14];
  const float* Wo  = (const float*)d_in[15];
  const float* bo  = (const float*)d_in[16];
  const float* ff_w1 = (const float*)d_in[17];
  const float* ff_b1 = (const float*)d_in[18];
  const float* ff_w2 = (const float*)d_in[19];
  const float* ff_b2 = (const float*)d_in[20];
  const float* pkm_wq   = (const float*)d_in[21];
  const float* pkm_keys = (const float*)d_in[22];
  const float* pkm_vals = (const float*)d_in[23];
  const float* norm_g = (const float*)d_in[24];
  const float* norm_b = (const float*)d_in[25];
  const float* hw1 = (const float*)d_in[26];
  const float* hb1 = (const float*)d_in[27];

  float* ws = (float*)d_ws;
  float* x1v  = ws;
  float* x2v  = ws + 2048000;
  float* hbuf = ws + 4096000;
  float* scrA = ws + 6144000;
  float* qk     = scrA;
  float* vv     = scrA + 2048000;
  float* so     = scrA + 4096000;
  float* slse   = scrA + 12288000;
  int*   buckets= (int*)(scrA + 12800000);
  int*   stp    = (int*)(scrA + 13312000);
  int*   undo   = (int*)(scrA + 13824000);
  float* attn_o = scrA + 14336000;
  float* big    = scrA;
  float* dotsb  = scrA;
  float* Mbuf   = ws + 22528000;

  embed_kernel<<<16000, 128, 0, stream>>>(x_mcc, x_amt, x_hour, x_wday,
      emb_mcc, emb_amt, emb_hour, emb_wday, x1v, x2v);

  int ffi = 0, pki = 0;
  for (int l = 0; l < 8; ++l) {
    ln_kernel<<<16000, 64, 0, stream>>>(x2v, nullptr, ln1_g + l*128, ln1_b + l*128, hbuf);
    { dim3 g(250, 2); mfma_matmul_kernel<<<g, 256, 0, stream>>>(hbuf, Wqk + (size_t)l*16384, nullptr, qk, 16000, 128, 128, MM_SPLIT); }
    { dim3 g(250, 2); mfma_matmul_kernel<<<g, 256, 0, stream>>>(hbuf, Wv  + (size_t)l*16384, nullptr, vv, 16000, 128, 128, MM_SPLIT); }
    bucket_kernel<<<500, 256, 0, stream>>>(qk, rot, buckets);
    sort_kernel<<<512, 64, 0, stream>>>(buckets, stp, undo);
    attn_chunk_kernel<<<20480, 64, 0, stream>>>(qk, vv, stp, x_mcc, so, slse);
    combine_kernel<<<8000, 256, 0, stream>>>(so, slse, undo, attn_o);
    { dim3 g(250, 2); mfma_matmul_kernel<<<g, 256, 0, stream>>>(attn_o, Wo + (size_t)l*16384, bo + l*128, x1v, 16000, 128, 128, MM_RES); }
    ln_kernel<<<16000, 64, 0, stream>>>(x1v, nullptr, ln2_g + l*128, ln2_b + l*128, hbuf);
    if (l == 3 || l == 6) {
      pkm_m_kernel<<<8, 256, 0, stream>>>(pkm_wq + (size_t)pki*65536, pkm_keys + (size_t)pki*65536, Mbuf);
      { dim3 g(250, 16); mfma_matmul_kernel<<<g, 256, 0, stream>>>(hbuf, Mbuf, nullptr, dotsb, 16000, 1024, 128, 0); }
      pkm_select_kernel<<<16000, 256, 0, stream>>>(dotsb, pkm_vals + (size_t)pki*2097152, x2v);
      ++pki;
    } else {
      { dim3 g(250, 8); mfma_matmul_kernel<<<g, 256, 0, stream>>>(hbuf, ff_w1 + (size_t)ffi*65536, ff_b1 + ffi*512, big, 16000, 512, 128, MM_GELU); }
      { dim3 g(250, 2); mfma_matmul_kernel<<<g, 256, 0, stream>>>(big, ff_w2 + (size_t)ffi*65536, ff_b2 + ffi*128, x2v, 16000, 128, 512, MM_RES); }
      ++ffi;
    }
  }
  ln_kernel<<<16000, 64, 0, stream>>>(x1v, x2v, norm_g, norm_b, hbuf);

  float* out = (float*)d_out;
  float* hid = scrA;
  const float* w2s[4] = {(const float*)d_in[28], (const float*)d_in[30], (const float*)d_in[32], (const float*)d_in[34]};
  const float* b2s[4] = {(const float*)d_in[29], (const float*)d_in[31], (const float*)d_in[33], (const float*)d_in[35]};
  const int ns[4] = {350, 100, 25, 8};
  size_t ooff = 0;
  for (int i = 0; i < 4; ++i) {
    { dim3 g(250, 2); mfma_matmul_kernel<<<g, 256, 0, stream>>>(hbuf, hw1 + (size_t)i*16384, hb1 + i*128, hid, 16000, 128, 128, MM_GELU); }
    { dim3 g(250, (unsigned)((ns[i]+63)/64)); mfma_matmul_kernel<<<g, 256, 0, stream>>>(hid, w2s[i], b2s[i], out + ooff, 16000, ns[i], 128, 0); }
    ooff += (size_t)16000 * ns[i];
  }
}

// Round 5
// 2557.219 us; speedup vs baseline: 2.1914x; 1.4496x over previous
//
#include <hip/hip_runtime.h>
#include <math.h>

#define MM_GELU 1
#define MM_RES 2
#define MM_SPLIT 4

typedef __attribute__((ext_vector_type(8))) short bfrag;
typedef __attribute__((ext_vector_type(4))) float f32x4;

__device__ inline unsigned short f2bf_rne(float f) {
  unsigned u = __float_as_uint(f);
  unsigned r = u + 0x7FFFu + ((u >> 16) & 1u);
  return (unsigned short)(r >> 16);
}
__device__ inline float bf2f(unsigned short h) {
  return __uint_as_float(((unsigned)h) << 16);
}

// ---------------- embedding + positional encoding ----------------
__global__ __launch_bounds__(128) void embed_kernel(
    const int* __restrict__ xm, const int* __restrict__ xa,
    const int* __restrict__ xh, const int* __restrict__ xw,
    const float* __restrict__ em, const float* __restrict__ ea,
    const float* __restrict__ eh, const float* __restrict__ ew,
    float* __restrict__ x1, float* __restrict__ x2) {
  int row = blockIdx.x;
  int d = threadIdx.x;
  int s = row % 1000;
  float v;
  if (d < 64)       v = em[xm[row]*64 + d];
  else if (d < 96)  v = ea[xa[row]*32 + (d-64)];
  else if (d < 112) v = eh[xh[row]*16 + (d-96)];
  else              v = ew[xw[row]*16 + (d-112)];
  int i = d >> 1;
  float dv = expf((float)(2*i) * (-9.21034037198f/128.f));
  float ang = (float)s * dv;
  v += (d & 1) ? cosf(ang) : sinf(ang);
  x1[row*128 + d] = v;
  x2[row*128 + d] = v;
}

// ---------------- layernorm (4 rows per block, one wave each) ----------------
__global__ __launch_bounds__(256) void ln_kernel(
    const float* __restrict__ x, const float* __restrict__ xb,
    const float* __restrict__ g, const float* __restrict__ b,
    float* __restrict__ out) {
  int row = blockIdx.x * 4 + (threadIdx.x >> 6);
  int t = threadIdx.x & 63;
  float v0 = x[row*128 + t], v1 = x[row*128 + 64 + t];
  if (xb) { v0 = 0.5f*(v0 + xb[row*128 + t]); v1 = 0.5f*(v1 + xb[row*128 + 64 + t]); }
  float sum = v0 + v1;
  #pragma unroll
  for (int o = 32; o > 0; o >>= 1) sum += __shfl_xor(sum, o);
  float mean = sum * (1.f/128.f);
  float d0 = v0 - mean, d1 = v1 - mean;
  float vs = d0*d0 + d1*d1;
  #pragma unroll
  for (int o = 32; o > 0; o >>= 1) vs += __shfl_xor(vs, o);
  float rstd = rsqrtf(vs*(1.f/128.f) + 1e-5f);
  out[row*128 + t]      = d0*rstd*g[t]    + b[t];
  out[row*128 + 64 + t] = d1*rstd*g[t+64] + b[t+64];
}

// ---------------- MFMA bf16x3 matmul: C = act(A[M,K] @ W[K,N] + bias) ----------------
__global__ __launch_bounds__(256) void mfma_matmul_kernel(
    const float* __restrict__ A, const float* __restrict__ W,
    const float* __restrict__ bias, float* __restrict__ C,
    int M, int N, int K, int flags) {
  __shared__ __align__(16) unsigned short Ah[64*40], Al[64*40], Bh[64*40], Bl[64*40];
  int tid = threadIdx.x;
  int bm = blockIdx.x * 64, bn = blockIdx.y * 64;
  int w = tid >> 6, lane = tid & 63;
  int l15 = lane & 15, kg = lane >> 4;
  f32x4 acc[4];
  #pragma unroll
  for (int t = 0; t < 4; ++t) { acc[t][0]=0.f; acc[t][1]=0.f; acc[t][2]=0.f; acc[t][3]=0.f; }
  int arr = tid >> 2, akc = (tid & 3) * 8;
  int bcol = tid >> 2, bk0 = (tid & 3) * 8;

  for (int k0 = 0; k0 < K; k0 += 32) {
    {
      const float* ap = A + (size_t)(bm + arr) * K + k0 + akc;
      float4 fa = *(const float4*)(ap);
      float4 fb = *(const float4*)(ap + 4);
      float av8[8] = {fa.x, fa.y, fa.z, fa.w, fb.x, fb.y, fb.z, fb.w};
      bfrag vh, vl;
      #pragma unroll
      for (int j = 0; j < 8; ++j) {
        unsigned short h = f2bf_rne(av8[j]);
        vh[j] = (short)h;
        vl[j] = (short)f2bf_rne(av8[j] - bf2f(h));
      }
      *(bfrag*)&Ah[arr*40 + akc] = vh;
      *(bfrag*)&Al[arr*40 + akc] = vl;
    }
    {
      int c = bn + bcol;
      float bv8[8];
      #pragma unroll
      for (int j = 0; j < 8; ++j) {
        int kk = k0 + bk0 + j;
        bv8[j] = (c < N) ? W[(size_t)kk * N + c] : 0.f;
      }
      #pragma unroll
      for (int j = 0; j < 8; j += 2) {
        unsigned short h0 = f2bf_rne(bv8[j]),   h1 = f2bf_rne(bv8[j+1]);
        unsigned short l0 = f2bf_rne(bv8[j]   - bf2f(h0));
        unsigned short l1 = f2bf_rne(bv8[j+1] - bf2f(h1));
        *(unsigned*)&Bh[bcol*40 + bk0 + j] = ((unsigned)h1 << 16) | h0;
        *(unsigned*)&Bl[bcol*40 + bk0 + j] = ((unsigned)l1 << 16) | l0;
      }
    }
    __syncthreads();
    int am = w*16 + l15;
    bfrag a_h = *(const bfrag*)&Ah[am*40 + kg*8];
    bfrag a_l = *(const bfrag*)&Al[am*40 + kg*8];
    #pragma unroll
    for (int t = 0; t < 4; ++t) {
      int nn = t*16 + l15;
      bfrag b_h = *(const bfrag*)&Bh[nn*40 + kg*8];
      bfrag b_l = *(const bfrag*)&Bl[nn*40 + kg*8];
      acc[t] = __builtin_amdgcn_mfma_f32_16x16x32_bf16(a_h, b_h, acc[t], 0, 0, 0);
      acc[t] = __builtin_amdgcn_mfma_f32_16x16x32_bf16(a_h, b_l, acc[t], 0, 0, 0);
      acc[t] = __builtin_amdgcn_mfma_f32_16x16x32_bf16(a_l, b_h, acc[t], 0, 0, 0);
    }
    __syncthreads();
  }
  #pragma unroll
  for (int t = 0; t < 4; ++t) {
    int col = bn + t*16 + l15;
    if (col < N) {
      #pragma unroll
      for (int r = 0; r < 4; ++r) {
        int row = bm + w*16 + kg*4 + r;
        float val = acc[t][r];
        if (bias) val += bias[col];
        if (flags & MM_GELU) val = 0.5f*val*(1.f + erff(val*0.70710678118f));
        size_t oi;
        if (flags & MM_SPLIT) {
          int bb = row / 1000, ss = row % 1000;
          int hd = col >> 4, dd = col & 15;
          oi = (((size_t)(bb*8 + hd))*1000 + ss)*16 + dd;
        } else {
          oi = (size_t)row*N + col;
        }
        if (flags & MM_RES) C[oi] += val; else C[oi] = val;
      }
    }
  }
}

// ---------------- LSH bucket assignment ----------------
__global__ __launch_bounds__(256) void bucket_kernel(
    const float* __restrict__ qk, const float* __restrict__ rot,
    int* __restrict__ buckets) {
  int idx = blockIdx.x*256 + threadIdx.x;
  if (idx >= 128000) return;
  int bh = idx / 1000, s = idx % 1000;
  float q[16];
  #pragma unroll
  for (int d = 0; d < 16; ++d) q[d] = qk[(bh*1000+s)*16 + d];
  #pragma unroll 1
  for (int r = 0; r < 4; ++r) {
    float rv[20];
    #pragma unroll
    for (int n = 0; n < 20; ++n) {
      float acc = 0.f;
      #pragma unroll
      for (int d = 0; d < 16; ++d) acc += q[d]*rot[(d*4 + r)*20 + n];
      rv[n] = acc;
    }
    float best = -INFINITY; int bi = 0;
    #pragma unroll
    for (int n = 0; n < 40; ++n) {
      float val = (n < 20) ? rv[n] : -rv[n-20];
      if (val > best) { best = val; bi = n; }
    }
    buckets[(bh*4 + r)*1000 + s] = bi;
  }
}

// ---------------- stable counting sort per (bh, round): bitwise-ballot ranks ----------------
__global__ __launch_bounds__(64) void sort_kernel(
    const int* __restrict__ buckets, int* __restrict__ st, int* __restrict__ undo) {
  int bh = blockIdx.x >> 2;
  int r = blockIdx.x & 3;
  const int* bkt = buckets + (bh*4 + r)*1000;
  __shared__ int off[40];
  int lane = threadIdx.x;
  if (lane < 40) off[lane] = 0;
  __syncthreads();
  unsigned long long below = (lane == 63) ? 0x7FFFFFFFFFFFFFFFull : ((1ull << lane) - 1ull);
  // pass 1: per-bucket counts (leader of each same-bucket group adds its popcount)
  for (int c = 0; c < 16; ++c) {
    int s = c*64 + lane;
    bool valid = (s < 1000);
    int b = valid ? bkt[s] : 0;
    unsigned long long mask = __ballot(valid);
    #pragma unroll
    for (int bit = 0; bit < 6; ++bit) {
      unsigned long long vote = __ballot((b >> bit) & 1);
      mask &= ((b >> bit) & 1) ? vote : ~vote;
    }
    if (valid) {
      int rank = (int)__popcll(mask & below);
      if (rank == 0) off[b] += (int)__popcll(mask);
    }
    __syncthreads();
  }
  if (lane == 0) {
    int acc = 0;
    for (int bb = 0; bb < 40; ++bb) { int cn = off[bb]; off[bb] = acc; acc += cn; }
  }
  __syncthreads();
  int base = bh*4000 + r*1000;
  // pass 2: stable placement with running offsets
  for (int c = 0; c < 16; ++c) {
    int s = c*64 + lane;
    bool valid = (s < 1000);
    int b = valid ? bkt[s] : 0;
    unsigned long long mask = __ballot(valid);
    #pragma unroll
    for (int bit = 0; bit < 6; ++bit) {
      unsigned long long vote = __ballot((b >> bit) & 1);
      mask &= ((b >> bit) & 1) ? vote : ~vote;
    }
    if (valid) {
      int myoff = off[b];
      int rank = (int)__popcll(mask & below);
      int slot = myoff + rank;
      st[base + slot] = s;
      undo[base + s] = r*1000 + slot;
      if (rank == 0) off[b] = myoff + (int)__popcll(mask);
    }
    __syncthreads();
  }
}

// ---------------- per-chunk attention: 2 lanes per query, register softmax ----------------
__global__ __launch_bounds__(64) void attn_chunk_kernel(
    const float* __restrict__ qk, const float* __restrict__ v,
    const int* __restrict__ st, const int* __restrict__ xm,
    float* __restrict__ so, float* __restrict__ slse) {
  int blk = blockIdx.x;
  int bh = blk / 160;
  int n = blk % 160;
  int b = bh >> 3;
  int lane = threadIdx.x;
  __shared__ __align__(16) float RAW[50][20];
  __shared__ __align__(16) float BV[50][20];
  __shared__ float RSQ[50];
  __shared__ int TKV[50], MKV[50];
  int pn = (n + 159) % 160;
  if (lane < 50) {
    int slot = (lane < 25) ? (n*25 + lane) : (pn*25 + (lane - 25));
    int t = st[bh*4000 + slot];
    TKV[lane] = t;
    MKV[lane] = (xm[b*1000 + t] != 0) ? 1 : 0;
  }
  __syncthreads();
  // cooperative vectorized load of 50 qk rows and 50 v rows
  for (int e = lane; e < 200; e += 64) {
    int rr = e >> 2, j = (e & 3) * 4;
    int t = TKV[rr];
    const float* qr = qk + ((size_t)bh*1000 + t)*16 + j;
    const float* vr = v  + ((size_t)bh*1000 + t)*16 + j;
    *(float4*)&RAW[rr][j] = *(const float4*)qr;
    *(float4*)&BV[rr][j]  = *(const float4*)vr;
  }
  __syncthreads();
  if (lane < 50) {
    float ss = 1e-9f;
    #pragma unroll
    for (int d = 0; d < 16; ++d) ss += RAW[lane][d]*RAW[lane][d];
    RSQ[lane] = rsqrtf(ss);
  }
  __syncthreads();
  if (lane < 50) {
    int q = lane % 25, h = lane / 25;
    int partner = (h == 0) ? lane + 25 : lane - 25;
    float sq[16];
    #pragma unroll
    for (int j = 0; j < 4; ++j) {
      float4 f = *(const float4*)&RAW[q][j*4];
      sq[j*4+0]=f.x; sq[j*4+1]=f.y; sq[j*4+2]=f.z; sq[j*4+3]=f.w;
    }
    int tq = TKV[q], mq = MKV[q];
    float p[25];
    #pragma unroll
    for (int i = 0; i < 25; ++i) {
      int k = h*25 + i;
      float acc = 0.f;
      #pragma unroll
      for (int j = 0; j < 4; ++j) {
        float4 f = *(const float4*)&RAW[k][j*4];
        acc += sq[j*4+0]*f.x + sq[j*4+1]*f.y + sq[j*4+2]*f.z + sq[j*4+3]*f.w;
      }
      acc *= 0.25f * RSQ[k];
      int tk = TKV[k], mk = MKV[k];
      if (!(mq && mk)) acc = -1e9f;
      if (tq < tk) acc = -1e9f;
      if (tq == tk) acc = -5e4f;
      p[i] = acc;
    }
    float m = -INFINITY;
    #pragma unroll
    for (int i = 0; i < 25; ++i) m = fmaxf(m, p[i]);
    m = fmaxf(m, __shfl(m, partner));
    float S = 0.f;
    #pragma unroll
    for (int i = 0; i < 25; ++i) { p[i] = expf(p[i] - m); S += p[i]; }
    S += __shfl(S, partner);
    float lse = m + logf(S);
    float rS = 1.f / S;
    float o[16];
    #pragma unroll
    for (int d = 0; d < 16; ++d) o[d] = 0.f;
    #pragma unroll
    for (int i = 0; i < 25; ++i) {
      int k = h*25 + i;
      float wt = p[i];
      #pragma unroll
      for (int j = 0; j < 4; ++j) {
        float4 f = *(const float4*)&BV[k][j*4];
        o[j*4+0] += wt*f.x; o[j*4+1] += wt*f.y; o[j*4+2] += wt*f.z; o[j*4+3] += wt*f.w;
      }
    }
    #pragma unroll
    for (int d = 0; d < 16; ++d) o[d] += __shfl(o[d], partner);
    if (h == 0) {
      int slot = n*25 + q;
      float* op = so + ((size_t)bh*4000 + slot)*16;
      #pragma unroll
      for (int j = 0; j < 4; ++j) {
        float4 f;
        f.x = o[j*4+0]*rS; f.y = o[j*4+1]*rS; f.z = o[j*4+2]*rS; f.w = o[j*4+3]*rS;
        *(float4*)(op + j*4) = f;
      }
      slse[bh*4000 + slot] = lse;
    }
  }
}

// ---------------- unsort + combine hash rounds + merge heads ----------------
__global__ __launch_bounds__(256) void combine_kernel(
    const float* __restrict__ so, const float* __restrict__ slse,
    const int* __restrict__ undo, float* __restrict__ ao) {
  int idx = blockIdx.x*256 + threadIdx.x;
  if (idx >= 2048000) return;
  int d = idx & 15;
  int s = (idx >> 4) % 1000;
  int bh = idx / 16000;
  int b = bh >> 3, hd = bh & 7;
  int s0 = undo[bh*4000 + s];
  int s1 = undo[bh*4000 + 1000 + s];
  int s2 = undo[bh*4000 + 2000 + s];
  int s3 = undo[bh*4000 + 3000 + s];
  float l0 = slse[bh*4000 + s0], l1 = slse[bh*4000 + s1];
  float l2 = slse[bh*4000 + s2], l3 = slse[bh*4000 + s3];
  float m = fmaxf(fmaxf(l0,l1), fmaxf(l2,l3));
  float w0 = expf(l0-m), w1 = expf(l1-m), w2 = expf(l2-m), w3 = expf(l3-m);
  float rs = 1.f/(w0+w1+w2+w3);
  const float* base = so + (size_t)bh*4000*16;
  float o = w0*base[s0*16+d] + w1*base[s1*16+d] + w2*base[s2*16+d] + w3*base[s3*16+d];
  ao[((size_t)b*1000 + s)*128 + hd*16 + d] = o * rs;
}

// ---------------- PKM prep: M[k, (h,p,n)] ----------------
__global__ __launch_bounds__(256) void pkm_m_kernel(
    const float* __restrict__ Wq, const float* __restrict__ keys,
    float* __restrict__ M) {
  int hp = blockIdx.x;
  int h = hp >> 1, p = hp & 1;
  int tid = threadIdx.x;
  __shared__ float Ks[128][65];
  for (int e = tid; e < 8192; e += 256) {
    int n = e >> 6, d = e & 63;
    Ks[n][d] = keys[((size_t)(h*128 + n)*2 + p)*64 + d];
  }
  __syncthreads();
  int k = tid >> 1;
  int nbase = (tid & 1) * 64;
  float wk[64];
  const float* wq = Wq + (size_t)k*512 + h*128 + p*64;
  #pragma unroll
  for (int d = 0; d < 64; ++d) wk[d] = wq[d];
  for (int n = 0; n < 64; ++n) {
    int nn = nbase + n;
    float acc = 0.f;
    #pragma unroll
    for (int d = 0; d < 64; ++d) acc += wk[d]*Ks[nn][d];
    M[(size_t)k*1024 + hp*128 + nn] = acc;
  }
}

// ---------------- PKM select: 8 waves, one 128-sort each; even waves finish ----------------
__device__ inline unsigned long long pk_key(float v, int idx) {
  unsigned u = __float_as_uint(v);
  u = (u & 0x80000000u) ? ~u : (u | 0x80000000u);
  unsigned kv = ~u;
  return ((unsigned long long)kv << 32) | (unsigned)idx;
}
__device__ inline float pk_val(unsigned long long key) {
  unsigned m = ~(unsigned)(key >> 32);
  return (m & 0x80000000u) ? __uint_as_float(m & 0x7FFFFFFFu) : __uint_as_float(~m);
}

__global__ __launch_bounds__(512) void pkm_select_kernel(
    const float* __restrict__ dots, const float* __restrict__ values,
    float* __restrict__ x2out) {
  int row = blockIdx.x;
  int tid = threadIdx.x;
  int w = tid >> 6;
  int lane = tid & 63;
  int h = w >> 1, p = w & 1;
  __shared__ float SVAL[4][2][16];
  __shared__ int SIDX[4][2][16];
  __shared__ float OUT[4][128];
  const float* dr = dots + (size_t)row*1024 + h*256 + p*128;
  // ---- each wave: full bitonic sort of its 128 dots (2 elems/lane) ----
  {
    unsigned long long k0 = pk_key(dr[lane], lane);
    unsigned long long k1 = pk_key(dr[64 + lane], 64 + lane);
    #pragma unroll 1
    for (int k = 2; k <= 128; k <<= 1) {
      #pragma unroll 1
      for (int j = k >> 1; j >= 1; j >>= 1) {
        if (j == 64) {
          unsigned long long lo = (k0 < k1) ? k0 : k1;
          unsigned long long hi = (k0 < k1) ? k1 : k0;
          k0 = lo; k1 = hi;
        } else {
          unsigned long long p0 = __shfl_xor(k0, j);
          unsigned long long p1 = __shfl_xor(k1, j);
          bool low = ((lane & j) == 0);
          bool up0 = ((lane & k) == 0);
          bool up1 = (((lane + 64) & k) == 0);
          bool t0 = (low == up0) ? (p0 < k0) : (p0 > k0);
          bool t1 = (low == up1) ? (p1 < k1) : (p1 > k1);
          if (t0) k0 = p0;
          if (t1) k1 = p1;
        }
      }
    }
    if (lane < 16) {
      SVAL[h][p][lane] = pk_val(k0);
      SIDX[h][p][lane] = (int)(unsigned)(k0 & 0xFFFFFFFFull);
    }
  }
  __syncthreads();
  if (p == 0) {
    // ---- 256-combo top-16: 50 staircase candidates (kx+1)(ky+1)<=16 ----
    int kx, ky;
    if      (lane < 16) { kx = 0; ky = lane; }
    else if (lane < 24) { kx = 1; ky = lane - 16; }
    else if (lane < 29) { kx = 2; ky = lane - 24; }
    else if (lane < 33) { kx = 3; ky = lane - 29; }
    else if (lane < 36) { kx = 4; ky = lane - 33; }
    else if (lane < 38) { kx = 5; ky = lane - 36; }
    else if (lane < 40) { kx = 6; ky = lane - 38; }
    else if (lane < 42) { kx = 7; ky = lane - 40; }
    else                { kx = 8 + (lane - 42); ky = 0; }
    unsigned long long key;
    if (lane < 50) {
      float cv = SVAL[h][0][kx] + SVAL[h][1][ky];
      key = pk_key(cv, kx*16 + ky);
    } else {
      key = ~0ull;
    }
    #pragma unroll 1
    for (int k = 2; k <= 64; k <<= 1) {
      #pragma unroll 1
      for (int j = k >> 1; j >= 1; j >>= 1) {
        unsigned long long pk = __shfl_xor(key, j);
        bool low = ((lane & j) == 0);
        bool up = ((lane & k) == 0);
        bool take = (low == up) ? (pk < key) : (pk > key);
        if (take) key = pk;
      }
    }
    float myv = pk_val(key);
    int pos = (int)(key & 0xFFull);
    int myfi = SIDX[h][0][pos >> 4] * 128 + SIDX[h][1][pos & 15];
    float fs0 = __shfl(myv, 0);
    float osum0 = 0.f, osum1 = 0.f, wsum = 0.f;
    #pragma unroll
    for (int k = 0; k < 16; ++k) {
      float fv = __shfl(myv, k);
      int fik = __shfl(myfi, k);
      float wgk = expf(fv - fs0);
      wsum += wgk;
      const float* vr = values + (size_t)fik * 128;
      osum0 += wgk * vr[lane];
      osum1 += wgk * vr[lane + 64];
    }
    float rs = 1.f / wsum;
    OUT[h][lane] = osum0 * rs;
    OUT[h][lane + 64] = osum1 * rs;
  }
  __syncthreads();
  if (tid < 128) {
    float r = OUT[0][tid] + OUT[1][tid] + OUT[2][tid] + OUT[3][tid];
    x2out[(size_t)row*128 + tid] += r;
  }
}

// ---------------- host ----------------
extern "C" void kernel_launch(void* const* d_in, const int* in_sizes, int n_in,
                              void* d_out, int out_size, void* d_ws, size_t ws_size,
                              hipStream_t stream) {
  (void)in_sizes; (void)n_in; (void)out_size; (void)ws_size;
  const int* x_mcc  = (const int*)d_in[0];
  const int* x_amt  = (const int*)d_in[1];
  const int* x_hour = (const int*)d_in[2];
  const int* x_wday = (const int*)d_in[3];
  const float* emb_mcc  = (const float*)d_in[4];
  const float* emb_amt  = (const float*)d_in[5];
  const float* emb_hour = (const float*)d_in[6];
  const float* emb_wday = (const float*)d_in[7];
  const float* rot   = (const float*)d_in[8];
  const float* ln1_g = (const float*)d_in[9];
  const float* ln1_b = (const float*)d_in[10];
  const float* ln2_g = (const float*)d_in[11];
  const float* ln2_b = (const float*)d_in[12];
  const float* Wqk = (const float*)d_in[13];
  const float* Wv  = (const float*)d_in[14];
  const float* Wo  = (const float*)d_in[15];
  const float* bo  = (const float*)d_in[16];
  const float* ff_w1 = (const float*)d_in[17];
  const float* ff_b1 = (const float*)d_in[18];
  const float* ff_w2 = (const float*)d_in[19];
  const float* ff_b2 = (const float*)d_in[20];
  const float* pkm_wq   = (const float*)d_in[21];
  const float* pkm_keys = (const float*)d_in[22];
  const float* pkm_vals = (const float*)d_in[23];
  const float* norm_g = (const float*)d_in[24];
  const float* norm_b = (const float*)d_in[25];
  const float* hw1 = (const float*)d_in[26];
  const float* hb1 = (const float*)d_in[27];

  float* ws = (float*)d_ws;
  float* x1v  = ws;
  float* x2v  = ws + 2048000;
  float* hbuf = ws + 4096000;
  float* scrA = ws + 6144000;
  float* qk     = scrA;
  float* vv     = scrA + 2048000;
  float* so     = scrA + 4096000;
  float* slse   = scrA + 12288000;
  int*   buckets= (int*)(scrA + 12800000);
  int*   stp    = (int*)(scrA + 13312000);
  int*   undo   = (int*)(scrA + 13824000);
  float* attn_o = scrA + 14336000;
  float* big    = scrA;
  float* dotsb  = scrA;
  float* Mbuf   = ws + 22528000;

  embed_kernel<<<16000, 128, 0, stream>>>(x_mcc, x_amt, x_hour, x_wday,
      emb_mcc, emb_amt, emb_hour, emb_wday, x1v, x2v);

  int ffi = 0, pki = 0;
  for (int l = 0; l < 8; ++l) {
    ln_kernel<<<4000, 256, 0, stream>>>(x2v, nullptr, ln1_g + l*128, ln1_b + l*128, hbuf);
    { dim3 g(250, 2); mfma_matmul_kernel<<<g, 256, 0, stream>>>(hbuf, Wqk + (size_t)l*16384, nullptr, qk, 16000, 128, 128, MM_SPLIT); }
    { dim3 g(250, 2); mfma_matmul_kernel<<<g, 256, 0, stream>>>(hbuf, Wv  + (size_t)l*16384, nullptr, vv, 16000, 128, 128, MM_SPLIT); }
    bucket_kernel<<<500, 256, 0, stream>>>(qk, rot, buckets);
    sort_kernel<<<512, 64, 0, stream>>>(buckets, stp, undo);
    attn_chunk_kernel<<<20480, 64, 0, stream>>>(qk, vv, stp, x_mcc, so, slse);
    combine_kernel<<<8000, 256, 0, stream>>>(so, slse, undo, attn_o);
    { dim3 g(250, 2); mfma_matmul_kernel<<<g, 256, 0, stream>>>(attn_o, Wo + (size_t)l*16384, bo + l*128, x1v, 16000, 128, 128, MM_RES); }
    ln_kernel<<<4000, 256, 0, stream>>>(x1v, nullptr, ln2_g + l*128, ln2_b + l*128, hbuf);
    if (l == 3 || l == 6) {
      pkm_m_kernel<<<8, 256, 0, stream>>>(pkm_wq + (size_t)pki*65536, pkm_keys + (size_t)pki*65536, Mbuf);
      { dim3 g(250, 16); mfma_matmul_kernel<<<g, 256, 0, stream>>>(hbuf, Mbuf, nullptr, dotsb, 16000, 1024, 128, 0); }
      pkm_select_kernel<<<16000, 512, 0, stream>>>(dotsb, pkm_vals + (size_t)pki*2097152, x2v);
      ++pki;
    } else {
      { dim3 g(250, 8); mfma_matmul_kernel<<<g, 256, 0, stream>>>(hbuf, ff_w1 + (size_t)ffi*65536, ff_b1 + ffi*512, big, 16000, 512, 128, MM_GELU); }
      { dim3 g(250, 2); mfma_matmul_kernel<<<g, 256, 0, stream>>>(big, ff_w2 + (size_t)ffi*65536, ff_b2 + ffi*128, x2v, 16000, 128, 512, MM_RES); }
      ++ffi;
    }
  }
  ln_kernel<<<4000, 256, 0, stream>>>(x1v, x2v, norm_g, norm_b, hbuf);

  float* out = (float*)d_out;
  float* hid = scrA;
  const float* w2s[4] = {(const float*)d_in[28], (const float*)d_in[30], (const float*)d_in[32], (const float*)d_in[34]};
  const float* b2s[4] = {(const float*)d_in[29], (const float*)d_in[31], (const float*)d_in[33], (const float*)d_in[35]};
  const int ns[4] = {350, 100, 25, 8};
  size_t ooff = 0;
  for (int i = 0; i < 4; ++i) {
    { dim3 g(250, 2); mfma_matmul_kernel<<<g, 256, 0, stream>>>(hbuf, hw1 + (size_t)i*16384, hb1 + i*128, hid, 16000, 128, 128, MM_GELU); }
    { dim3 g(250, (unsigned)((ns[i]+63)/64)); mfma_matmul_kernel<<<g, 256, 0, stream>>>(hid, w2s[i], b2s[i], out + ooff, 16000, ns[i], 128, 0); }
    ooff += (size_t)16000 * ns[i];
  }
}

// Round 8
// 2553.121 us; speedup vs baseline: 2.1949x; 1.0016x over previous
//
#include <hip/hip_runtime.h>
#include <math.h>

#define MM_GELU 1
#define MM_RES 2
#define MM_SPLIT 4
#define MM_SPLITONLY 8

typedef __attribute__((ext_vector_type(8))) short bfrag;
typedef __attribute__((ext_vector_type(4))) float f32x4;

__device__ inline unsigned short f2bf_rne(float f) {
  unsigned u = __float_as_uint(f);
  unsigned r = u + 0x7FFFu + ((u >> 16) & 1u);
  return (unsigned short)(r >> 16);
}
__device__ inline float bf2f(unsigned short h) {
  return __uint_as_float(((unsigned)h) << 16);
}

// ---------------- embedding + positional encoding ----------------
__global__ __launch_bounds__(128) void embed_kernel(
    const int* __restrict__ xm, const int* __restrict__ xa,
    const int* __restrict__ xh, const int* __restrict__ xw,
    const float* __restrict__ em, const float* __restrict__ ea,
    const float* __restrict__ eh, const float* __restrict__ ew,
    float* __restrict__ x1, float* __restrict__ x2) {
  int row = blockIdx.x;
  int d = threadIdx.x;
  int s = row % 1000;
  float v;
  if (d < 64)       v = em[xm[row]*64 + d];
  else if (d < 96)  v = ea[xa[row]*32 + (d-64)];
  else if (d < 112) v = eh[xh[row]*16 + (d-96)];
  else              v = ew[xw[row]*16 + (d-112)];
  int i = d >> 1;
  float dv = expf((float)(2*i) * (-9.21034037198f/128.f));
  float ang = (float)s * dv;
  v += (d & 1) ? cosf(ang) : sinf(ang);
  x1[row*128 + d] = v;
  x2[row*128 + d] = v;
}

// ---------------- layernorm -> bf16 hi/lo split output ----------------
__global__ __launch_bounds__(256) void ln_kernel(
    const float* __restrict__ x, const float* __restrict__ xb,
    const float* __restrict__ g, const float* __restrict__ b,
    unsigned short* __restrict__ oh, unsigned short* __restrict__ ol) {
  int row = blockIdx.x * 4 + (threadIdx.x >> 6);
  int t = threadIdx.x & 63;
  float v0 = x[row*128 + t], v1 = x[row*128 + 64 + t];
  if (xb) { v0 = 0.5f*(v0 + xb[row*128 + t]); v1 = 0.5f*(v1 + xb[row*128 + 64 + t]); }
  float sum = v0 + v1;
  #pragma unroll
  for (int o = 32; o > 0; o >>= 1) sum += __shfl_xor(sum, o);
  float mean = sum * (1.f/128.f);
  float d0 = v0 - mean, d1 = v1 - mean;
  float vs = d0*d0 + d1*d1;
  #pragma unroll
  for (int o = 32; o > 0; o >>= 1) vs += __shfl_xor(vs, o);
  float rstd = rsqrtf(vs*(1.f/128.f) + 1e-5f);
  float y0 = d0*rstd*g[t]    + b[t];
  float y1 = d1*rstd*g[t+64] + b[t+64];
  unsigned short h0 = f2bf_rne(y0), h1 = f2bf_rne(y1);
  oh[row*128 + t]      = h0;
  ol[row*128 + t]      = f2bf_rne(y0 - bf2f(h0));
  oh[row*128 + 64 + t] = h1;
  ol[row*128 + 64 + t] = f2bf_rne(y1 - bf2f(h1));
}

// ---------------- one-time weight transpose + bf16 hi/lo split ----------------
// src [K][N] f32 -> hiT/loT [N][K] bf16. blockIdx.z batches matrices.
__global__ __launch_bounds__(256) void splitT_kernel(
    const float* __restrict__ src, unsigned short* __restrict__ hiT,
    unsigned short* __restrict__ loT, int K, int N,
    long srcStride, long dstStride) {
  src += (size_t)blockIdx.z * srcStride;
  hiT += (size_t)blockIdx.z * dstStride;
  loT += (size_t)blockIdx.z * dstStride;
  int n0 = blockIdx.x * 64, k0 = blockIdx.y * 64;
  __shared__ unsigned short sH[64][68], sL[64][68];
  int tid = threadIdx.x;
  int c = tid & 63, r4 = tid >> 6;
  #pragma unroll
  for (int rr = 0; rr < 16; ++rr) {
    int r = r4 + rr*4;
    float val = (n0 + c < N) ? src[(size_t)(k0 + r)*N + n0 + c] : 0.f;
    unsigned short h = f2bf_rne(val);
    sH[r][c] = h;
    sL[r][c] = f2bf_rne(val - bf2f(h));
  }
  __syncthreads();
  #pragma unroll
  for (int rr = 0; rr < 16; ++rr) {
    int n = r4 + rr*4;
    if (n0 + n < N) {
      hiT[(size_t)(n0 + n)*K + k0 + c] = sH[c][n];
      loT[(size_t)(n0 + n)*K + k0 + c] = sL[c][n];
    }
  }
}

// ---------------- bf16x3 MFMA matmul on pre-split operands ----------------
// A: Ah/Al [M][K] bf16; B: BhT/BlT [N][K] bf16. C = act(A@B + bias).
__global__ __launch_bounds__(256) void mm_bf16_kernel(
    const unsigned short* __restrict__ Ah, const unsigned short* __restrict__ Al,
    const unsigned short* __restrict__ BhT, const unsigned short* __restrict__ BlT,
    const float* __restrict__ bias, float* __restrict__ C,
    unsigned short* __restrict__ Ch, unsigned short* __restrict__ Cl,
    int M, int N, int K, int flags) {
  __shared__ __align__(16) unsigned short sAh[64][72], sAl[64][72], sBh[64][72], sBl[64][72];
  int tid = threadIdx.x;
  int bm = blockIdx.x * 64, bn = blockIdx.y * 64;
  int w = tid >> 6, lane = tid & 63;
  int l15 = lane & 15, kg = lane >> 4;
  f32x4 acc[4];
  #pragma unroll
  for (int t = 0; t < 4; ++t) { acc[t][0]=0.f; acc[t][1]=0.f; acc[t][2]=0.f; acc[t][3]=0.f; }

  for (int k0 = 0; k0 < K; k0 += 64) {
    #pragma unroll
    for (int uu = 0; uu < 2; ++uu) {
      int u = tid + uu*256;
      int rr = u >> 3, cc = u & 7;
      size_t ga = (size_t)(bm + rr)*K + k0 + cc*8;
      *(bfrag*)&sAh[rr][cc*8] = *(const bfrag*)(Ah + ga);
      *(bfrag*)&sAl[rr][cc*8] = *(const bfrag*)(Al + ga);
      int n = bn + rr;
      if (n < N) {
        size_t gb = (size_t)n*K + k0 + cc*8;
        *(bfrag*)&sBh[rr][cc*8] = *(const bfrag*)(BhT + gb);
        *(bfrag*)&sBl[rr][cc*8] = *(const bfrag*)(BlT + gb);
      } else {
        bfrag z = {0,0,0,0,0,0,0,0};
        *(bfrag*)&sBh[rr][cc*8] = z;
        *(bfrag*)&sBl[rr][cc*8] = z;
      }
    }
    __syncthreads();
    #pragma unroll
    for (int ks = 0; ks < 2; ++ks) {
      int am = w*16 + l15;
      bfrag a_h = *(const bfrag*)&sAh[am][ks*32 + kg*8];
      bfrag a_l = *(const bfrag*)&sAl[am][ks*32 + kg*8];
      #pragma unroll
      for (int t = 0; t < 4; ++t) {
        int nn = t*16 + l15;
        bfrag b_h = *(const bfrag*)&sBh[nn][ks*32 + kg*8];
        bfrag b_l = *(const bfrag*)&sBl[nn][ks*32 + kg*8];
        acc[t] = __builtin_amdgcn_mfma_f32_16x16x32_bf16(a_h, b_h, acc[t], 0, 0, 0);
        acc[t] = __builtin_amdgcn_mfma_f32_16x16x32_bf16(a_h, b_l, acc[t], 0, 0, 0);
        acc[t] = __builtin_amdgcn_mfma_f32_16x16x32_bf16(a_l, b_h, acc[t], 0, 0, 0);
      }
    }
    __syncthreads();
  }
  #pragma unroll
  for (int t = 0; t < 4; ++t) {
    int col = bn + t*16 + l15;
    if (col < N) {
      #pragma unroll
      for (int r = 0; r < 4; ++r) {
        int row = bm + w*16 + kg*4 + r;
        float val = acc[t][r];
        if (bias) val += bias[col];
        if (flags & MM_GELU) val = 0.5f*val*(1.f + erff(val*0.70710678118f));
        size_t oi;
        if (flags & MM_SPLIT) {
          int bb = row / 1000, ss = row % 1000;
          int hd = col >> 4, dd = col & 15;
          oi = (((size_t)(bb*8 + hd))*1000 + ss)*16 + dd;
        } else {
          oi = (size_t)row*N + col;
        }
        if (flags & MM_SPLITONLY) {
          unsigned short h = f2bf_rne(val);
          Ch[oi] = h;
          Cl[oi] = f2bf_rne(val - bf2f(h));
        } else if (flags & MM_RES) C[oi] += val;
        else C[oi] = val;
      }
    }
  }
}

// ---------------- LSH bucket assignment ----------------
__global__ __launch_bounds__(256) void bucket_kernel(
    const float* __restrict__ qk, const float* __restrict__ rot,
    int* __restrict__ buckets) {
  int idx = blockIdx.x*256 + threadIdx.x;
  if (idx >= 128000) return;
  int bh = idx / 1000, s = idx % 1000;
  float q[16];
  #pragma unroll
  for (int d = 0; d < 16; ++d) q[d] = qk[(bh*1000+s)*16 + d];
  #pragma unroll 1
  for (int r = 0; r < 4; ++r) {
    float rv[20];
    #pragma unroll
    for (int n = 0; n < 20; ++n) {
      float acc = 0.f;
      #pragma unroll
      for (int d = 0; d < 16; ++d) acc += q[d]*rot[(d*4 + r)*20 + n];
      rv[n] = acc;
    }
    float best = -INFINITY; int bi = 0;
    #pragma unroll
    for (int n = 0; n < 40; ++n) {
      float val = (n < 20) ? rv[n] : -rv[n-20];
      if (val > best) { best = val; bi = n; }
    }
    buckets[(bh*4 + r)*1000 + s] = bi;
  }
}

// ---------------- stable counting sort per (bh, round): bitwise-ballot ranks ----------------
__global__ __launch_bounds__(64) void sort_kernel(
    const int* __restrict__ buckets, int* __restrict__ st, int* __restrict__ undo) {
  int bh = blockIdx.x >> 2;
  int r = blockIdx.x & 3;
  const int* bkt = buckets + (bh*4 + r)*1000;
  __shared__ int off[40];
  int lane = threadIdx.x;
  if (lane < 40) off[lane] = 0;
  __syncthreads();
  unsigned long long below = (lane == 63) ? 0x7FFFFFFFFFFFFFFFull : ((1ull << lane) - 1ull);
  for (int c = 0; c < 16; ++c) {
    int s = c*64 + lane;
    bool valid = (s < 1000);
    int b = valid ? bkt[s] : 0;
    unsigned long long mask = __ballot(valid);
    #pragma unroll
    for (int bit = 0; bit < 6; ++bit) {
      unsigned long long vote = __ballot((b >> bit) & 1);
      mask &= ((b >> bit) & 1) ? vote : ~vote;
    }
    if (valid) {
      int rank = (int)__popcll(mask & below);
      if (rank == 0) off[b] += (int)__popcll(mask);
    }
    __syncthreads();
  }
  if (lane == 0) {
    int acc = 0;
    for (int bb = 0; bb < 40; ++bb) { int cn = off[bb]; off[bb] = acc; acc += cn; }
  }
  __syncthreads();
  int base = bh*4000 + r*1000;
  for (int c = 0; c < 16; ++c) {
    int s = c*64 + lane;
    bool valid = (s < 1000);
    int b = valid ? bkt[s] : 0;
    unsigned long long mask = __ballot(valid);
    #pragma unroll
    for (int bit = 0; bit < 6; ++bit) {
      unsigned long long vote = __ballot((b >> bit) & 1);
      mask &= ((b >> bit) & 1) ? vote : ~vote;
    }
    if (valid) {
      int myoff = off[b];
      int rank = (int)__popcll(mask & below);
      int slot = myoff + rank;
      st[base + slot] = s;
      undo[base + s] = r*1000 + slot;
      if (rank == 0) off[b] = myoff + (int)__popcll(mask);
    }
    __syncthreads();
  }
}

// ---------------- per-chunk attention: 2 lanes per query, register softmax ----------------
__global__ __launch_bounds__(64) void attn_chunk_kernel(
    const float* __restrict__ qk, const float* __restrict__ v,
    const int* __restrict__ st, const int* __restrict__ xm,
    float* __restrict__ so, float* __restrict__ slse) {
  int blk = blockIdx.x;
  int bh = blk / 160;
  int n = blk % 160;
  int b = bh >> 3;
  int lane = threadIdx.x;
  __shared__ __align__(16) float RAW[50][20];
  __shared__ __align__(16) float BV[50][20];
  __shared__ float RSQ[50];
  __shared__ int TKV[50], MKV[50];
  int pn = (n + 159) % 160;
  if (lane < 50) {
    int slot = (lane < 25) ? (n*25 + lane) : (pn*25 + (lane - 25));
    int t = st[bh*4000 + slot];
    TKV[lane] = t;
    MKV[lane] = (xm[b*1000 + t] != 0) ? 1 : 0;
  }
  __syncthreads();
  for (int e = lane; e < 200; e += 64) {
    int rr = e >> 2, j = (e & 3) * 4;
    int t = TKV[rr];
    const float* qr = qk + ((size_t)bh*1000 + t)*16 + j;
    const float* vr = v  + ((size_t)bh*1000 + t)*16 + j;
    *(float4*)&RAW[rr][j] = *(const float4*)qr;
    *(float4*)&BV[rr][j]  = *(const float4*)vr;
  }
  __syncthreads();
  if (lane < 50) {
    float ss = 1e-9f;
    #pragma unroll
    for (int d = 0; d < 16; ++d) ss += RAW[lane][d]*RAW[lane][d];
    RSQ[lane] = rsqrtf(ss);
  }
  __syncthreads();
  if (lane < 50) {
    int q = lane % 25, h = lane / 25;
    int partner = (h == 0) ? lane + 25 : lane - 25;
    float sq[16];
    #pragma unroll
    for (int j = 0; j < 4; ++j) {
      float4 f = *(const float4*)&RAW[q][j*4];
      sq[j*4+0]=f.x; sq[j*4+1]=f.y; sq[j*4+2]=f.z; sq[j*4+3]=f.w;
    }
    int tq = TKV[q], mq = MKV[q];
    float p[25];
    #pragma unroll
    for (int i = 0; i < 25; ++i) {
      int k = h*25 + i;
      float acc = 0.f;
      #pragma unroll
      for (int j = 0; j < 4; ++j) {
        float4 f = *(const float4*)&RAW[k][j*4];
        acc += sq[j*4+0]*f.x + sq[j*4+1]*f.y + sq[j*4+2]*f.z + sq[j*4+3]*f.w;
      }
      acc *= 0.25f * RSQ[k];
      int tk = TKV[k], mk = MKV[k];
      if (!(mq && mk)) acc = -1e9f;
      if (tq < tk) acc = -1e9f;
      if (tq == tk) acc = -5e4f;
      p[i] = acc;
    }
    float m = -INFINITY;
    #pragma unroll
    for (int i = 0; i < 25; ++i) m = fmaxf(m, p[i]);
    m = fmaxf(m, __shfl(m, partner));
    float S = 0.f;
    #pragma unroll
    for (int i = 0; i < 25; ++i) { p[i] = expf(p[i] - m); S += p[i]; }
    S += __shfl(S, partner);
    float lse = m + logf(S);
    float rS = 1.f / S;
    float o[16];
    #pragma unroll
    for (int d = 0; d < 16; ++d) o[d] = 0.f;
    #pragma unroll
    for (int i = 0; i < 25; ++i) {
      int k = h*25 + i;
      float wt = p[i];
      #pragma unroll
      for (int j = 0; j < 4; ++j) {
        float4 f = *(const float4*)&BV[k][j*4];
        o[j*4+0] += wt*f.x; o[j*4+1] += wt*f.y; o[j*4+2] += wt*f.z; o[j*4+3] += wt*f.w;
      }
    }
    #pragma unroll
    for (int d = 0; d < 16; ++d) o[d] += __shfl(o[d], partner);
    if (h == 0) {
      int slot = n*25 + q;
      float* op = so + ((size_t)bh*4000 + slot)*16;
      #pragma unroll
      for (int j = 0; j < 4; ++j) {
        float4 f;
        f.x = o[j*4+0]*rS; f.y = o[j*4+1]*rS; f.z = o[j*4+2]*rS; f.w = o[j*4+3]*rS;
        *(float4*)(op + j*4) = f;
      }
      slse[bh*4000 + slot] = lse;
    }
  }
}

// ---------------- unsort + combine + merge heads -> bf16 hi/lo ----------------
__global__ __launch_bounds__(256) void combine_kernel(
    const float* __restrict__ so, const float* __restrict__ slse,
    const int* __restrict__ undo, unsigned short* __restrict__ aoh,
    unsigned short* __restrict__ aol) {
  int idx = blockIdx.x*256 + threadIdx.x;
  if (idx >= 2048000) return;
  int d = idx & 15;
  int s = (idx >> 4) % 1000;
  int bh = idx / 16000;
  int b = bh >> 3, hd = bh & 7;
  int s0 = undo[bh*4000 + s];
  int s1 = undo[bh*4000 + 1000 + s];
  int s2 = undo[bh*4000 + 2000 + s];
  int s3 = undo[bh*4000 + 3000 + s];
  float l0 = slse[bh*4000 + s0], l1 = slse[bh*4000 + s1];
  float l2 = slse[bh*4000 + s2], l3 = slse[bh*4000 + s3];
  float m = fmaxf(fmaxf(l0,l1), fmaxf(l2,l3));
  float w0 = expf(l0-m), w1 = expf(l1-m), w2 = expf(l2-m), w3 = expf(l3-m);
  float rs = 1.f/(w0+w1+w2+w3);
  const float* base = so + (size_t)bh*4000*16;
  float o = (w0*base[s0*16+d] + w1*base[s1*16+d] + w2*base[s2*16+d] + w3*base[s3*16+d]) * rs;
  size_t oi = ((size_t)b*1000 + s)*128 + hd*16 + d;
  unsigned short h = f2bf_rne(o);
  aoh[oi] = h;
  aol[oi] = f2bf_rne(o - bf2f(h));
}

// ---------------- PKM prep: M[k, (h,p,n)] ----------------
__global__ __launch_bounds__(256) void pkm_m_kernel(
    const float* __restrict__ Wq, const float* __restrict__ keys,
    float* __restrict__ M) {
  int hp = blockIdx.x;
  int h = hp >> 1, p = hp & 1;
  int tid = threadIdx.x;
  __shared__ float Ks[128][65];
  for (int e = tid; e < 8192; e += 256) {
    int n = e >> 6, d = e & 63;
    Ks[n][d] = keys[((size_t)(h*128 + n)*2 + p)*64 + d];
  }
  __syncthreads();
  int k = tid >> 1;
  int nbase = (tid & 1) * 64;
  float wk[64];
  const float* wq = Wq + (size_t)k*512 + h*128 + p*64;
  #pragma unroll
  for (int d = 0; d < 64; ++d) wk[d] = wq[d];
  for (int n = 0; n < 64; ++n) {
    int nn = nbase + n;
    float acc = 0.f;
    #pragma unroll
    for (int d = 0; d < 64; ++d) acc += wk[d]*Ks[nn][d];
    M[(size_t)k*1024 + hp*128 + nn] = acc;
  }
}

// ---------------- PKM select: dual concurrent 128-sorts + staircase ----------------
__device__ inline unsigned long long pk_key(float v, int idx) {
  unsigned u = __float_as_uint(v);
  u = (u & 0x80000000u) ? ~u : (u | 0x80000000u);
  unsigned kv = ~u;
  return ((unsigned long long)kv << 32) | (unsigned)idx;
}
__device__ inline float pk_val(unsigned long long key) {
  unsigned m = ~(unsigned)(key >> 32);
  return (m & 0x80000000u) ? __uint_as_float(m & 0x7FFFFFFFu) : __uint_as_float(~m);
}

__global__ __launch_bounds__(256) void pkm_select_kernel(
    const float* __restrict__ dots, const float* __restrict__ values,
    float* __restrict__ x2out) {
  int row = blockIdx.x;
  int tid = threadIdx.x;
  int h = tid >> 6;         // head, one wave each
  int lane = tid & 63;
  __shared__ float OUT[4][128];
  const float* dr = dots + (size_t)row*1024 + h*256;
  // dual 128-element bitonic sorts (x segment and y segment), interleaved for ILP
  unsigned long long x0 = pk_key(dr[lane], lane);
  unsigned long long x1 = pk_key(dr[64 + lane], 64 + lane);
  unsigned long long y0 = pk_key(dr[128 + lane], lane);
  unsigned long long y1 = pk_key(dr[192 + lane], 64 + lane);
  #pragma unroll 1
  for (int k = 2; k <= 128; k <<= 1) {
    #pragma unroll 1
    for (int j = k >> 1; j >= 1; j >>= 1) {
      if (j == 64) {
        unsigned long long lo, hi;
        lo = (x0 < x1) ? x0 : x1; hi = (x0 < x1) ? x1 : x0; x0 = lo; x1 = hi;
        lo = (y0 < y1) ? y0 : y1; hi = (y0 < y1) ? y1 : y0; y0 = lo; y1 = hi;
      } else {
        unsigned long long px0 = __shfl_xor(x0, j);
        unsigned long long px1 = __shfl_xor(x1, j);
        unsigned long long py0 = __shfl_xor(y0, j);
        unsigned long long py1 = __shfl_xor(y1, j);
        bool low = ((lane & j) == 0);
        bool up0 = ((lane & k) == 0);
        bool up1 = (((lane + 64) & k) == 0);
        bool d0 = (low == up0);
        bool d1 = (low == up1);
        if (d0 ? (px0 < x0) : (px0 > x0)) x0 = px0;
        if (d1 ? (px1 < x1) : (px1 > x1)) x1 = px1;
        if (d0 ? (py0 < y0) : (py0 > y0)) y0 = py0;
        if (d1 ? (py1 < y1) : (py1 > y1)) y1 = py1;
      }
    }
  }
  // lanes 0..15 of x0/y0 hold sorted top-16 of each segment
  float xv = pk_val(x0);
  float yv = pk_val(y0);
  int xi = (int)(unsigned)(x0 & 0xFFFFFFFFull);
  int yi = (int)(unsigned)(y0 & 0xFFFFFFFFull);
  // 256-combo top-16: 50 staircase candidates (kx+1)(ky+1)<=16
  int kx, ky;
  if      (lane < 16) { kx = 0; ky = lane; }
  else if (lane < 24) { kx = 1; ky = lane - 16; }
  else if (lane < 29) { kx = 2; ky = lane - 24; }
  else if (lane < 33) { kx = 3; ky = lane - 29; }
  else if (lane < 36) { kx = 4; ky = lane - 33; }
  else if (lane < 38) { kx = 5; ky = lane - 36; }
  else if (lane < 40) { kx = 6; ky = lane - 38; }
  else if (lane < 42) { kx = 7; ky = lane - 40; }
  else                { kx = 8 + (lane - 42); ky = 0; }
  float sxk = __shfl(xv, kx);
  float syk = __shfl(yv, ky);
  unsigned long long key = (lane < 50) ? pk_key(sxk + syk, kx*16 + ky) : ~0ull;
  #pragma unroll 1
  for (int k = 2; k <= 64; k <<= 1) {
    #pragma unroll 1
    for (int j = k >> 1; j >= 1; j >>= 1) {
      unsigned long long pk = __shfl_xor(key, j);
      bool low = ((lane & j) == 0);
      bool up = ((lane & k) == 0);
      bool take = (low == up) ? (pk < key) : (pk > key);
      if (take) key = pk;
    }
  }
  float myv = pk_val(key);
  int pos = (int)(key & 0xFFull);
  int ix = __shfl(xi, pos >> 4);
  int iy = __shfl(yi, pos & 15);
  int myfi = ix*128 + iy;
  float fs0 = __shfl(myv, 0);
  float osum0 = 0.f, osum1 = 0.f, wsum = 0.f;
  #pragma unroll
  for (int k = 0; k < 16; ++k) {
    float fv = __shfl(myv, k);
    int fik = __shfl(myfi, k);
    float wgk = expf(fv - fs0);
    wsum += wgk;
    const float* vr = values + (size_t)fik * 128;
    osum0 += wgk * vr[lane];
    osum1 += wgk * vr[lane + 64];
  }
  float rs = 1.f / wsum;
  OUT[h][lane] = osum0 * rs;
  OUT[h][lane + 64] = osum1 * rs;
  __syncthreads();
  if (tid < 128) {
    float r = OUT[0][tid] + OUT[1][tid] + OUT[2][tid] + OUT[3][tid];
    x2out[(size_t)row*128 + tid] += r;
  }
}

// ---------------- host ----------------
extern "C" void kernel_launch(void* const* d_in, const int* in_sizes, int n_in,
                              void* d_out, int out_size, void* d_ws, size_t ws_size,
                              hipStream_t stream) {
  (void)in_sizes; (void)n_in; (void)out_size; (void)ws_size;
  const int* x_mcc  = (const int*)d_in[0];
  const int* x_amt  = (const int*)d_in[1];
  const int* x_hour = (const int*)d_in[2];
  const int* x_wday = (const int*)d_in[3];
  const float* emb_mcc  = (const float*)d_in[4];
  const float* emb_amt  = (const float*)d_in[5];
  const float* emb_hour = (const float*)d_in[6];
  const float* emb_wday = (const float*)d_in[7];
  const float* rot   = (const float*)d_in[8];
  const float* ln1_g = (const float*)d_in[9];
  const float* ln1_b = (const float*)d_in[10];
  const float* ln2_g = (const float*)d_in[11];
  const float* ln2_b = (const float*)d_in[12];
  const float* Wqk = (const float*)d_in[13];
  const float* Wv  = (const float*)d_in[14];
  const float* Wo  = (const float*)d_in[15];
  const float* bo  = (const float*)d_in[16];
  const float* ff_w1 = (const float*)d_in[17];
  const float* ff_b1 = (const float*)d_in[18];
  const float* ff_w2 = (const float*)d_in[19];
  const float* ff_b2 = (const float*)d_in[20];
  const float* pkm_wq   = (const float*)d_in[21];
  const float* pkm_keys = (const float*)d_in[22];
  const float* pkm_vals = (const float*)d_in[23];
  const float* norm_g = (const float*)d_in[24];
  const float* norm_b = (const float*)d_in[25];
  const float* hw1 = (const float*)d_in[26];
  const float* hb1 = (const float*)d_in[27];

  float* ws = (float*)d_ws;
  float* x1v  = ws;
  float* x2v  = ws + 2048000;
  float* hbuf = ws + 4096000;              // bf16 hi/lo splits of LN output
  float* scrA = ws + 6144000;
  float* qk     = scrA;
  float* vv     = scrA + 2048000;
  float* so     = scrA + 4096000;
  float* slse   = scrA + 12288000;
  int*   buckets= (int*)(scrA + 12800000);
  int*   stp    = (int*)(scrA + 13312000);
  int*   undo   = (int*)(scrA + 13824000);
  float* attn_o = scrA + 14336000;         // bf16 hi/lo splits of combine output
  float* dotsb  = scrA;
  float* Mbuf   = ws + 22528000;

  unsigned short* hbuf_h = (unsigned short*)hbuf;
  unsigned short* hbuf_l = hbuf_h + 2048000;
  unsigned short* ao_h = (unsigned short*)attn_o;
  unsigned short* ao_l = ao_h + 2048000;
  unsigned short* big_h = (unsigned short*)scrA;     // FF hidden splits (attn scratch dead)
  unsigned short* big_l = big_h + 8192000;
  unsigned short* hid_h = ao_h;                       // head hidden splits (final phase)
  unsigned short* hid_l = ao_l;

  unsigned short* wsp = (unsigned short*)(ws + 22700000);
  unsigned short* WqkT_h = wsp;              // 8 x 128x128
  unsigned short* WqkT_l = wsp + 131072;
  unsigned short* WvT_h  = wsp + 262144;
  unsigned short* WvT_l  = wsp + 393216;
  unsigned short* WoT_h  = wsp + 524288;
  unsigned short* WoT_l  = wsp + 655360;
  unsigned short* f1T_h  = wsp + 786432;     // 6 x 512x128 (T of 128x512), 65536 each
  unsigned short* f1T_l  = wsp + 1179648;
  unsigned short* f2T_h  = wsp + 1572864;    // 6 x 128x512 (T of 512x128), 65536 each
  unsigned short* f2T_l  = wsp + 1966080;
  unsigned short* MT_h   = wsp + 2359296;    // 1024x128 (T of 128x1024)
  unsigned short* MT_l   = wsp + 2490368;
  unsigned short* hw1T_h = wsp + 2621440;    // 4 x 128x128
  unsigned short* hw1T_l = wsp + 2686976;
  unsigned short* h2T_h  = wsp + 2752512;    // heads: (350+100+25+8)x128
  unsigned short* h2T_l  = wsp + 2814336;

  // ---- one-time weight splits (transposed) ----
  { dim3 g(2,2,8); splitT_kernel<<<g,256,0,stream>>>(Wqk, WqkT_h, WqkT_l, 128,128, 16384,16384); }
  { dim3 g(2,2,8); splitT_kernel<<<g,256,0,stream>>>(Wv,  WvT_h,  WvT_l,  128,128, 16384,16384); }
  { dim3 g(2,2,8); splitT_kernel<<<g,256,0,stream>>>(Wo,  WoT_h,  WoT_l,  128,128, 16384,16384); }
  { dim3 g(8,2,6); splitT_kernel<<<g,256,0,stream>>>(ff_w1, f1T_h, f1T_l, 128,512, 65536,65536); }
  { dim3 g(2,8,6); splitT_kernel<<<g,256,0,stream>>>(ff_w2, f2T_h, f2T_l, 512,128, 65536,65536); }
  { dim3 g(2,2,4); splitT_kernel<<<g,256,0,stream>>>(hw1, hw1T_h, hw1T_l, 128,128, 16384,16384); }
  const float* w2s[4] = {(const float*)d_in[28], (const float*)d_in[30], (const float*)d_in[32], (const float*)d_in[34]};
  const float* b2s[4] = {(const float*)d_in[29], (const float*)d_in[31], (const float*)d_in[33], (const float*)d_in[35]};
  const int ns[4] = {350, 100, 25, 8};
  const long h2off[4] = {0, 44800, 57600, 60800};
  for (int i = 0; i < 4; ++i) {
    dim3 g((ns[i]+63)/64, 2, 1);
    splitT_kernel<<<g,256,0,stream>>>(w2s[i], h2T_h + h2off[i], h2T_l + h2off[i], 128, ns[i], 0, 0);
  }

  embed_kernel<<<16000, 128, 0, stream>>>(x_mcc, x_amt, x_hour, x_wday,
      emb_mcc, emb_amt, emb_hour, emb_wday, x1v, x2v);

  int ffi = 0, pki = 0;
  for (int l = 0; l < 8; ++l) {
    ln_kernel<<<4000, 256, 0, stream>>>(x2v, nullptr, ln1_g + l*128, ln1_b + l*128, hbuf_h, hbuf_l);
    { dim3 g(250, 2); mm_bf16_kernel<<<g, 256, 0, stream>>>(hbuf_h, hbuf_l, WqkT_h + l*16384, WqkT_l + l*16384, nullptr, qk, nullptr, nullptr, 16000, 128, 128, MM_SPLIT); }
    { dim3 g(250, 2); mm_bf16_kernel<<<g, 256, 0, stream>>>(hbuf_h, hbuf_l, WvT_h + l*16384, WvT_l + l*16384, nullptr, vv, nullptr, nullptr, 16000, 128, 128, MM_SPLIT); }
    bucket_kernel<<<500, 256, 0, stream>>>(qk, rot, buckets);
    sort_kernel<<<512, 64, 0, stream>>>(buckets, stp, undo);
    attn_chunk_kernel<<<20480, 64, 0, stream>>>(qk, vv, stp, x_mcc, so, slse);
    combine_kernel<<<8000, 256, 0, stream>>>(so, slse, undo, ao_h, ao_l);
    { dim3 g(250, 2); mm_bf16_kernel<<<g, 256, 0, stream>>>(ao_h, ao_l, WoT_h + l*16384, WoT_l + l*16384, bo + l*128, x1v, nullptr, nullptr, 16000, 128, 128, MM_RES); }
    ln_kernel<<<4000, 256, 0, stream>>>(x1v, nullptr, ln2_g + l*128, ln2_b + l*128, hbuf_h, hbuf_l);
    if (l == 3 || l == 6) {
      pkm_m_kernel<<<8, 256, 0, stream>>>(pkm_wq + (size_t)pki*65536, pkm_keys + (size_t)pki*65536, Mbuf);
      { dim3 g(16, 2, 1); splitT_kernel<<<g,256,0,stream>>>(Mbuf, MT_h, MT_l, 128, 1024, 0, 0); }
      { dim3 g(250, 16); mm_bf16_kernel<<<g, 256, 0, stream>>>(hbuf_h, hbuf_l, MT_h, MT_l, nullptr, dotsb, nullptr, nullptr, 16000, 1024, 128, 0); }
      pkm_select_kernel<<<16000, 256, 0, stream>>>(dotsb, pkm_vals + (size_t)pki*2097152, x2v);
      ++pki;
    } else {
      { dim3 g(250, 8); mm_bf16_kernel<<<g, 256, 0, stream>>>(hbuf_h, hbuf_l, f1T_h + ffi*65536, f1T_l + ffi*65536, ff_b1 + ffi*512, nullptr, big_h, big_l, 16000, 512, 128, MM_GELU|MM_SPLITONLY); }
      { dim3 g(250, 2); mm_bf16_kernel<<<g, 256, 0, stream>>>(big_h, big_l, f2T_h + ffi*65536, f2T_l + ffi*65536, ff_b2 + ffi*128, x2v, nullptr, nullptr, 16000, 128, 512, MM_RES); }
      ++ffi;
    }
  }
  ln_kernel<<<4000, 256, 0, stream>>>(x1v, x2v, norm_g, norm_b, hbuf_h, hbuf_l);

  float* out = (float*)d_out;
  size_t ooff = 0;
  for (int i = 0; i < 4; ++i) {
    { dim3 g(250, 2); mm_bf16_kernel<<<g, 256, 0, stream>>>(hbuf_h, hbuf_l, hw1T_h + i*16384, hw1T_l + i*16384, hb1 + i*128, nullptr, hid_h, hid_l, 16000, 128, 128, MM_GELU|MM_SPLITONLY); }
    { dim3 g(250, (unsigned)((ns[i]+63)/64)); mm_bf16_kernel<<<g, 256, 0, stream>>>(hid_h, hid_l, h2T_h + h2off[i], h2T_l + h2off[i], b2s[i], out + ooff, nullptr, nullptr, 16000, ns[i], 128, 0); }
    ooff += (size_t)16000 * ns[i];
  }
}